// Round 7
// baseline (249.241 us; speedup 1.0000x reference)
//
#include <hip/hip_runtime.h>

typedef unsigned short u16;
typedef unsigned int u32;
typedef unsigned long long u64;
typedef _Float16 f16x8 __attribute__((ext_vector_type(8)));
typedef float f32x4 __attribute__((ext_vector_type(4)));

__device__ __forceinline__ u16 f2h(float f) {
  union { _Float16 h; u16 u; } c; c.h = (_Float16)f; return c.u;
}
__device__ __forceinline__ float h2f(u16 v) {
  union { u16 u; _Float16 h; } c; c.u = v; return (float)c.h;
}

__device__ __forceinline__ f32x4 mfma16(f16x8 a, f16x8 b, f32x4 c) {
  return __builtin_amdgcn_mfma_f32_16x16x32_f16(a, b, c, 0, 0, 0);
}

// 8 contiguous fp32 -> 8 fp16 (u16)
__device__ __forceinline__ void ld8f(const float* s, u16* o) {
  float4 a = *(const float4*)s;
  float4 b = *(const float4*)(s + 4);
  o[0] = f2h(a.x); o[1] = f2h(a.y); o[2] = f2h(a.z); o[3] = f2h(a.w);
  o[4] = f2h(b.x); o[5] = f2h(b.y); o[6] = f2h(b.z); o[7] = f2h(b.w);
}

// pack two float4-pairs (8 floats) to 8 fp16
__device__ __forceinline__ void cvt8(float4 a, float4 b, u16* o) {
  o[0] = f2h(a.x); o[1] = f2h(a.y); o[2] = f2h(a.z); o[3] = f2h(a.w);
  o[4] = f2h(b.x); o[5] = f2h(b.y); o[6] = f2h(b.z); o[7] = f2h(b.w);
}

// async global->LDS 16B direct load. LDS dest wave-uniform base; HW adds lane*16.
__device__ __forceinline__ void glds16(const u16* g, u16* l) {
  __builtin_amdgcn_global_load_lds(
      reinterpret_cast<const __attribute__((address_space(1))) u32*>(reinterpret_cast<u64>(g)),
      reinterpret_cast<__attribute__((address_space(3))) u32*>(reinterpret_cast<u64>(l)),
      16, 0, 0);
}

// ---------------------------------------------------------------------------
// Counted-vmcnt pipelined NT tile core (unchanged from r6).
// ---------------------------------------------------------------------------
template<int TM, int TN, int WM, int WN, int DEPTH>
__device__ __forceinline__ void gemm_core(const u16* __restrict__ A, int lda,
                                          const u16* __restrict__ B, int ldb,
                                          int ksteps, u16* sA, u16* sB, f32x4 acc[TM][TN]) {
  constexpr int NT = WM * WN * 64;
  constexpr int BM = WM * TM * 16, BN = WN * TN * 16;
  constexpr int TILEA = BM * 32, TILEB = BN * 32;   // u16 per buffer
  constexpr int APF = (BM * 4) / NT, BPF = (BN * 4) / NT;  // glds/thread
  constexpr int VPI = APF + BPF;                    // vmem issued per iter
  constexpr int PF = DEPTH - 2;                     // prefetch depth
  static_assert(PF == 1 || PF == 2, "");
  static_assert(APF >= 1 && BPF >= 1, "");

  const int t = threadIdx.x;
  const int lane = t & 63, wave = t >> 6;
  const int wm = wave / WN, wn = wave % WN;
  const int m16 = lane & 15, q4 = lane >> 4;

  int aoff[APF], asl[APF];
#pragma unroll
  for (int p = 0; p < APF; ++p) {
    int s = p * NT + t, row = s >> 2;
    int kc = (s & 3) ^ ((row >> 1) & 3);
    aoff[p] = row * lda + kc * 8;
    asl[p] = (p * NT + (wave << 6)) * 8;  // wave-uniform LDS u16 base
  }
  int boff[BPF], bsl[BPF];
#pragma unroll
  for (int p = 0; p < BPF; ++p) {
    int s = p * NT + t, row = s >> 2;
    int kc = (s & 3) ^ ((row >> 1) & 3);
    boff[p] = row * ldb + kc * 8;
    bsl[p] = (p * NT + (wave << 6)) * 8;
  }

  int aro[TM], bro[TN];
#pragma unroll
  for (int i = 0; i < TM; ++i) {
    int row = wm * TM * 16 + i * 16 + m16;
    aro[i] = row * 32 + ((q4 ^ ((row >> 1) & 3)) << 3);
  }
#pragma unroll
  for (int j = 0; j < TN; ++j) {
    int row = wn * TN * 16 + j * 16 + m16;
    bro[j] = row * 32 + ((q4 ^ ((row >> 1) & 3)) << 3);
  }

  // prologue: stage tiles 0..PF-1 into buffers 0..PF-1
#pragma unroll
  for (int j = 0; j < PF; ++j) {
    const u16* Aj = A + j * 32;
    u16* aS = sA + j * TILEA;
#pragma unroll
    for (int p = 0; p < APF; ++p) glds16(Aj + aoff[p], aS + asl[p]);
    const u16* Bj = B + j * 32;
    u16* bS = sB + j * TILEB;
#pragma unroll
    for (int p = 0; p < BPF; ++p) glds16(Bj + boff[p], bS + bsl[p]);
  }

  int cur = 0, stg = PF;
#pragma unroll 1
  for (int kt = 0; kt < ksteps; ++kt) {
    if (kt + PF < ksteps) {
      const u16* An = A + (size_t)(kt + PF) * 32;
      u16* aS = sA + stg * TILEA;
#pragma unroll
      for (int p = 0; p < APF; ++p) glds16(An + aoff[p], aS + asl[p]);
      const u16* Bn = B + (size_t)(kt + PF) * 32;
      u16* bS = sB + stg * TILEB;
#pragma unroll
      for (int p = 0; p < BPF; ++p) glds16(Bn + boff[p], bS + bsl[p]);
    }
    if (PF == 2 && kt + 2 < ksteps)
      asm volatile("s_waitcnt vmcnt(%0)" :: "n"(2 * VPI) : "memory");
    else if (kt + 1 < ksteps)
      asm volatile("s_waitcnt vmcnt(%0)" :: "n"(VPI) : "memory");
    else
      asm volatile("s_waitcnt vmcnt(0)" ::: "memory");
    __builtin_amdgcn_s_barrier();
    __builtin_amdgcn_sched_barrier(0);

    const u16* aR = sA + cur * TILEA;
    const u16* bR = sB + cur * TILEB;
    f16x8 af[TM], bv[TN];
#pragma unroll
    for (int i = 0; i < TM; ++i) af[i] = *(const f16x8*)&aR[aro[i]];
#pragma unroll
    for (int j = 0; j < TN; ++j) bv[j] = *(const f16x8*)&bR[bro[j]];
#pragma unroll
    for (int i = 0; i < TM; ++i)
#pragma unroll
      for (int j = 0; j < TN; ++j)
        acc[i][j] = mfma16(af[i], bv[j], acc[i][j]);

    cur = (cur + 1 == DEPTH) ? 0 : cur + 1;
    stg = (stg + 1 == DEPTH) ? 0 : stg + 1;
  }
}

// ---------------------------------------------------------------------------
// Merged prep.
// x-role blocks [0,1024): one 128(o)x128(n) tile per block — 512 B/row reads,
//   256 B/row writes (vs 256/128 B before: lifts DRAM page efficiency).
//   b = blk&7 -> XCD b (batch-local L2 for downstream consumers).
//   LDS transpose: u32-packed (o-pair) words, row stride 65 u32; write bank
//   = (n_local + rp)&31 with rp=t&63 spanning 64 -> 2-way (free); read b32
//   bank = (n + j)&31 -> 2-way (free).
// [1024,1536): q rows; [1536,1792): vwT; [1792,1920): kwh; 1920: beta=0.
// ---------------------------------------------------------------------------
__global__ __launch_bounds__(256) void prep_all_kernel(const float* __restrict__ x,
                                                       u16* __restrict__ xh, u16* __restrict__ xhT,
                                                       const float* __restrict__ q, u16* __restrict__ qh,
                                                       float* __restrict__ qs,
                                                       const float* __restrict__ vw, u16* __restrict__ vwT,
                                                       const float* __restrict__ kw, u16* __restrict__ kwh,
                                                       float* __restrict__ beta) {
  __shared__ __align__(16) u32 T[128 * 65];  // 33280 B
  int blk = blockIdx.x, t = threadIdx.x;
  if (blk < 1024) {
    int b = blk & 7, r = blk >> 3;       // XCD = batch
    int nt = r & 31, ot = r >> 5;        // n-tile (128 wide), o-tile (128 tall)
    int rp = t & 63, qw = t >> 6;        // o-pair index, n-chunk (wave)
    int o0 = ot * 128 + 2 * rp;
    int n0 = nt * 128 + qw * 32;
    const float* x0 = x + ((size_t)b * 512 + o0) * 4096 + n0;
    u16* xq = xh + ((size_t)b * 512 + o0) * 4096 + n0;

#pragma unroll
    for (int k = 0; k < 4; ++k) {
      float4 a0 = *(const float4*)(x0 + 8 * k);
      float4 a1 = *(const float4*)(x0 + 8 * k + 4);
      float4 b0 = *(const float4*)(x0 + 4096 + 8 * k);
      float4 b1 = *(const float4*)(x0 + 4096 + 8 * k + 4);
      u16 h0[8], h1[8];
      cvt8(a0, a1, h0);
      cvt8(b0, b1, h1);
      *(int4*)(xq + 8 * k) = *(int4*)h0;
      *(int4*)(xq + 4096 + 8 * k) = *(int4*)h1;
#pragma unroll
      for (int e = 0; e < 8; ++e)
        T[(qw * 32 + 8 * k + e) * 65 + rp] = (u32)h0[e] | ((u32)h1[e] << 16);
    }
    __syncthreads();

    // read: thread covers n-row = t>>1, o-half hh = t&1 (32 u32 = 64 o)
    int n = t >> 1, hh = t & 1;
    u32 v[32];
#pragma unroll
    for (int j = 0; j < 32; ++j) v[j] = T[n * 65 + hh * 32 + j];
    u16* xo = xhT + ((size_t)b * 4096 + nt * 128 + n) * 512 + ot * 128 + hh * 64;
#pragma unroll
    for (int j = 0; j < 8; ++j)
      *(int4*)(xo + 8 * j) = *(int4*)&v[4 * j];
  } else if (blk < 1536) {
    int row = blk - 1024;
    float s = 0.f;
#pragma unroll
    for (int p = 0; p < 2; ++p) {
      size_t i = (size_t)row * 4096 + p * 2048 + t * 8;
      u16 o[8];
      ld8f(q + i, o);
#pragma unroll
      for (int e = 0; e < 8; ++e) s += h2f(o[e]);
      *(int4*)&qh[i] = *(int4*)o;
    }
    for (int off = 32; off; off >>= 1) s += __shfl_xor(s, off);
    __shared__ float wsum[4];
    if ((t & 63) == 0) wsum[t >> 6] = s;
    __syncthreads();
    if (t == 0) qs[row] = wsum[0] + wsum[1] + wsum[2] + wsum[3];
  } else if (blk < 1792) {
    int bi = blk - 1536;
    u16* sT = (u16*)T;  // reuse (needs 32*33 u16)
    int bx = bi & 15, by = bi >> 4;
#pragma unroll
    for (int p = 0; p < 4; ++p) {
      int idx = p * 256 + t; int r = idx >> 5, c = idx & 31;
      sT[r * 33 + c] = f2h(vw[(size_t)(by * 32 + r) * 512 + bx * 32 + c]);
    }
    __syncthreads();
#pragma unroll
    for (int p = 0; p < 4; ++p) {
      int idx = p * 256 + t; int r = idx >> 5, c = idx & 31;
      vwT[(size_t)(bx * 32 + r) * 512 + by * 32 + c] = sT[c * 33 + r];
    }
  } else if (blk < 1920) {
    size_t i = ((size_t)(blk - 1792) * 256 + t) * 8;
    u16 o[8];
    ld8f(kw + i, o);
    *(int4*)&kwh[i] = *(int4*)o;
  } else {
    for (int i = t; i < 4096; i += 256) beta[i] = 0.f;
  }
}

// sgemm split-K, 128x128 tiles. 1-D grid 256, b = blk&7 -> XCD b: xh[b]
// (4 MB) stays in that XCD's L2 across all (och, jt, ks) re-reads.
__global__ __launch_bounds__(256) void sgemm_kernel(const u16* __restrict__ qh, const u16* __restrict__ xh,
                                                    float* __restrict__ Sp0, float* __restrict__ Sp1) {
  __shared__ __align__(16) u16 sA[4 * 128 * 32], sB[4 * 128 * 32];
  int blk = blockIdx.x;
  int b = blk & 7, r = blk >> 3;
  int och = r & 3, jt = (r >> 2) & 3, ks = r >> 4;
  int o0 = och * 128;
  f32x4 acc[4][4];
#pragma unroll
  for (int i = 0; i < 4; ++i)
#pragma unroll
    for (int j = 0; j < 4; ++j) acc[i][j] = (f32x4){0.f, 0.f, 0.f, 0.f};
  gemm_core<4, 4, 2, 2, 4>(qh + (size_t)jt * 128 * 4096 + (size_t)ks * 2048, 4096,
                           xh + ((size_t)b * 512 + o0) * 4096 + (size_t)ks * 2048, 4096,
                           64, sA, sB, acc);

  const int t = threadIdx.x, lane = t & 63, wave = t >> 6;
  const int wm = wave >> 1, wn = wave & 1, m16 = lane & 15, q4 = lane >> 4;
  float* Sp = ks ? Sp1 : Sp0;
  float* Ob = Sp + (size_t)b * 262144;
#pragma unroll
  for (int i = 0; i < 4; ++i)
#pragma unroll
    for (int j = 0; j < 4; ++j)
#pragma unroll
      for (int r2 = 0; r2 < 4; ++r2) {
        int y = jt * 128 + wm * 64 + i * 16 + q4 * 4 + r2;
        int o = o0 + wn * 64 + j * 16 + m16;
        Ob[(size_t)y * 512 + o] = acc[i][j][r2];
      }
}

// Sh = f2h(Sp0 + Sp1); b = blk&7 keeps it on XCD b (producer & consumer local)
__global__ __launch_bounds__(256) void sreduce_kernel(const float* __restrict__ Sp0,
                                                      const float* __restrict__ Sp1,
                                                      u16* __restrict__ Sh) {
  int blk = blockIdx.x;
  int b = blk & 7, r = blk >> 3;  // r in [0,128)
  size_t i = (size_t)b * 262144 + (size_t)r * 2048 + threadIdx.x * 8;
  float4 a0 = *(const float4*)(Sp0 + i);
  float4 a1 = *(const float4*)(Sp0 + i + 4);
  float4 b0 = *(const float4*)(Sp1 + i);
  float4 b1 = *(const float4*)(Sp1 + i + 4);
  a0.x += b0.x; a0.y += b0.y; a0.z += b0.z; a0.w += b0.w;
  a1.x += b1.x; a1.y += b1.y; a1.z += b1.z; a1.w += b1.w;
  u16 o[8];
  cvt8(a0, a1, o);
  *(int4*)&Sh[i] = *(int4*)o;
}

// E[b,x,y] = sum_o kw[x,o] * Sh[b][y][o]; XCD = b
__global__ __launch_bounds__(256) void egemm_kernel(const u16* __restrict__ kwh, const u16* __restrict__ Sh,
                                                    float* __restrict__ E) {
  __shared__ __align__(16) u16 sA[4 * 64 * 32], sB[4 * 64 * 32];
  int blk = blockIdx.x;
  int b = blk & 7, r = blk >> 3;
  int xt = r >> 3, yt = r & 7;
  f32x4 acc[2][2];
#pragma unroll
  for (int i = 0; i < 2; ++i)
#pragma unroll
    for (int j = 0; j < 2; ++j) acc[i][j] = (f32x4){0.f, 0.f, 0.f, 0.f};
  gemm_core<2, 2, 2, 2, 4>(kwh + (size_t)xt * 64 * 512, 512,
                           Sh + (size_t)b * 262144 + (size_t)yt * 64 * 512, 512, 16, sA, sB, acc);

  const int t = threadIdx.x, lane = t & 63, wave = t >> 6;
  const int wm = wave >> 1, wn = wave & 1, m16 = lane & 15, q4 = lane >> 4;
  float* O = E + ((size_t)b * 512 + xt * 64) * 512 + yt * 64;
#pragma unroll
  for (int i = 0; i < 2; ++i)
#pragma unroll
    for (int j = 0; j < 2; ++j)
#pragma unroll
      for (int r2 = 0; r2 < 4; ++r2) {
        int row = wm * 32 + i * 16 + q4 * 4 + r2;
        int col = wn * 32 + j * 16 + m16;
        O[(size_t)row * 512 + col] = acc[i][j][r2];
      }
}

// softmax over y; XCD = b (E[b] is L2-local from egemm)
__global__ __launch_bounds__(256) void softmax_kernel(const float* __restrict__ E, const float* __restrict__ qs,
                                                      const float* __restrict__ kb, const float* __restrict__ vb,
                                                      u16* __restrict__ attT, float* __restrict__ beta) {
  __shared__ float sE[16 * 516];
  __shared__ float sM[16], sS[16];
  int blk = blockIdx.x;
  int b = blk & 7, i0 = (blk >> 3) * 16;
  int t = threadIdx.x;
  const float* Eb = E + ((size_t)b * 512 + i0) * 512;
  for (int ch = 0; ch < 32; ++ch) {
    int idx = ch * 256 + t;
    int row = idx >> 9, col = idx & 511;
    sE[row * 516 + col] = Eb[(size_t)row * 512 + col] + kb[i0 + row] * qs[col];
  }
  __syncthreads();
  {
    int row = t >> 4, sub = t & 15;
    float mx = -1e30f;
    for (int ii = 0; ii < 32; ++ii) mx = fmaxf(mx, sE[row * 516 + sub + ii * 16]);
    for (int off = 8; off; off >>= 1) mx = fmaxf(mx, __shfl_xor(mx, off));
    float sm = 0.f;
    for (int ii = 0; ii < 32; ++ii) sm += __expf(sE[row * 516 + sub + ii * 16] - mx);
    for (int off = 8; off; off >>= 1) sm += __shfl_xor(sm, off);
    if (sub == 0) { sM[row] = mx; sS[row] = 1.f / sm; }
  }
  __syncthreads();
  float vbr = vb[i0 + (t & 15)];
  u16* Ob = attT + (size_t)b * 262144;
  for (int ch = 0; ch < 32; ++ch) {
    int idx = ch * 256 + t;
    int r = idx & 15, j = idx >> 4;
    float a = __expf(sE[r * 516 + j] - sM[r]) * sS[r];
    Ob[(size_t)j * 512 + i0 + r] = f2h(a);
    float part = a * vbr;
    for (int off = 8; off; off >>= 1) part += __shfl_xor(part, off);
    if (r == 0) atomicAdd(&beta[b * 512 + j], part);
  }
}

// W[b][c][o] = sum_x attT[b][c][x] * vwT[o][x]; XCD = b
__global__ __launch_bounds__(256) void wgemm_kernel(const u16* __restrict__ attT, const u16* __restrict__ vwT,
                                                    u16* __restrict__ W) {
  __shared__ __align__(16) u16 sA[4 * 64 * 32], sB[4 * 64 * 32];
  int blk = blockIdx.x;
  int b = blk & 7, r = blk >> 3;
  int ct = r >> 3, ot = r & 7;
  f32x4 acc[2][2];
#pragma unroll
  for (int i = 0; i < 2; ++i)
#pragma unroll
    for (int j = 0; j < 2; ++j) acc[i][j] = (f32x4){0.f, 0.f, 0.f, 0.f};
  gemm_core<2, 2, 2, 2, 4>(attT + (size_t)b * 262144 + (size_t)ct * 64 * 512, 512,
                           vwT + (size_t)ot * 64 * 512, 512, 16, sA, sB, acc);

  const int t = threadIdx.x, lane = t & 63, wave = t >> 6;
  const int wm = wave >> 1, wn = wave & 1, m16 = lane & 15, q4 = lane >> 4;
  u16* O = W + (size_t)b * 262144 + (size_t)(ct * 64) * 512 + ot * 64;
#pragma unroll
  for (int i = 0; i < 2; ++i)
#pragma unroll
    for (int j = 0; j < 2; ++j)
#pragma unroll
      for (int r2 = 0; r2 < 4; ++r2) {
        int row = wm * 32 + i * 16 + q4 * 4 + r2;
        int col = wn * 32 + j * 16 + m16;
        O[(size_t)row * 512 + col] = f2h(acc[i][j][r2]);
      }
}

// out = gamma*(W·xhT + beta) + x; XCD = b (W[b], xhT[b] L2-local)
__global__ __launch_bounds__(256) void outgemm_kernel(const u16* __restrict__ W, const u16* __restrict__ xhT,
                                                      const float* __restrict__ x, const float* __restrict__ beta,
                                                      const float* __restrict__ gm, float* __restrict__ out) {
  __shared__ __align__(16) u16 sA[4 * 128 * 32], sB[4 * 128 * 32];
  int blk = blockIdx.x;
  int b = blk & 7, r = blk >> 3;
  int nt = r & 31, ct = r >> 5;
  f32x4 acc[4][4];
#pragma unroll
  for (int i = 0; i < 4; ++i)
#pragma unroll
    for (int j = 0; j < 4; ++j) acc[i][j] = (f32x4){0.f, 0.f, 0.f, 0.f};
  gemm_core<4, 4, 2, 2, 4>(W + (size_t)b * 262144 + (size_t)ct * 128 * 512, 512,
                           xhT + (size_t)b * 2097152 + (size_t)nt * 128 * 512, 512, 16, sA, sB, acc);

  const int t = threadIdx.x, lane = t & 63, wave = t >> 6;
  const int wm = wave >> 1, wn = wave & 1, m16 = lane & 15, q4 = lane >> 4;
  float g = gm[0];
#pragma unroll
  for (int i = 0; i < 4; ++i)
#pragma unroll
    for (int j = 0; j < 4; ++j)
#pragma unroll
      for (int r2 = 0; r2 < 4; ++r2) {
        int c = ct * 128 + wm * 64 + i * 16 + q4 * 4 + r2;
        int n = nt * 128 + wn * 64 + j * 16 + m16;
        size_t idx = (size_t)b * 2097152 + (size_t)c * 4096 + n;
        out[idx] = g * (acc[i][j][r2] + beta[b * 512 + c]) + x[idx];
      }
}

extern "C" void kernel_launch(void* const* d_in, const int* in_sizes, int n_in,
                              void* d_out, int out_size, void* d_ws, size_t ws_size,
                              hipStream_t stream) {
  const float* x  = (const float*)d_in[0];
  const float* pq = (const float*)d_in[1];
  const float* kw = (const float*)d_in[2];
  const float* kb = (const float*)d_in[3];
  const float* vw = (const float*)d_in[4];
  const float* vb = (const float*)d_in[5];
  const float* gm = (const float*)d_in[6];
  float* out = (float*)d_out;

  // workspace: 94 MB
  char* ws = (char*)d_ws;
  u16*   xh   = (u16*)(ws);                            // [0,32M)  fp16 x [b][o][n]
  u16*   qh   = (u16*)(ws + (32ull << 20));            // [32,36M)
  u16*   Sh   = (u16*)(ws + (36ull << 20));            // [36,40M) reused as W after egemm
  u16*   W    = (u16*)(ws + (36ull << 20));
  float* E    = (float*)(ws + (40ull << 20));          // [40,48M) fp32; Sp0 during sgemm
  float* Sp0  = (float*)(ws + (40ull << 20));
  u16*   attT = (u16*)(ws + (48ull << 20));            // [48,52M)
  u16*   kwh  = (u16*)(ws + (52ull << 20));            // 512K
  u16*   vwT  = (u16*)(ws + (52ull << 20) + 524288);   // 512K
  char*  sm   = ws + (53ull << 20);                    // small region
  float* qs   = (float*)(sm);
  float* beta = (float*)(sm + 4096);                   // 16K
  u16*   xhT  = (u16*)(ws + (54ull << 20));            // [54,86M) fp16 x^T [b][n][o]
  float* Sp1  = (float*)(ws + (86ull << 20));          // [86,94M) split-K partial 1

  prep_all_kernel<<<dim3(1921), 256, 0, stream>>>(x, xh, xhT, pq, qh, qs, vw, vwT, kw, kwh, beta);
  sgemm_kernel<<<dim3(256), 256, 0, stream>>>(qh, xh, Sp0, Sp1);
  sreduce_kernel<<<dim3(1024), 256, 0, stream>>>(Sp0, Sp1, Sh);
  egemm_kernel<<<dim3(512), 256, 0, stream>>>(kwh, Sh, E);
  softmax_kernel<<<dim3(256), 256, 0, stream>>>(E, qs, kb, vb, attT, beta);
  wgemm_kernel<<<dim3(512), 256, 0, stream>>>(attT, vwT, W);
  outgemm_kernel<<<dim3(1024), 256, 0, stream>>>(W, xhT, x, beta, gm, out);
}

// Round 8
// 242.290 us; speedup vs baseline: 1.0287x; 1.0287x over previous
//
#include <hip/hip_runtime.h>

typedef unsigned short u16;
typedef unsigned int u32;
typedef unsigned long long u64;
typedef _Float16 f16x8 __attribute__((ext_vector_type(8)));
typedef float f32x4 __attribute__((ext_vector_type(4)));

__device__ __forceinline__ u16 f2h(float f) {
  union { _Float16 h; u16 u; } c; c.h = (_Float16)f; return c.u;
}
__device__ __forceinline__ float h2f(u16 v) {
  union { u16 u; _Float16 h; } c; c.u = v; return (float)c.h;
}

__device__ __forceinline__ f32x4 mfma16(f16x8 a, f16x8 b, f32x4 c) {
  return __builtin_amdgcn_mfma_f32_16x16x32_f16(a, b, c, 0, 0, 0);
}

// 8 contiguous fp32 -> 8 fp16 (u16)
__device__ __forceinline__ void ld8f(const float* s, u16* o) {
  float4 a = *(const float4*)s;
  float4 b = *(const float4*)(s + 4);
  o[0] = f2h(a.x); o[1] = f2h(a.y); o[2] = f2h(a.z); o[3] = f2h(a.w);
  o[4] = f2h(b.x); o[5] = f2h(b.y); o[6] = f2h(b.z); o[7] = f2h(b.w);
}

// pack two float4-pairs (8 floats) to 8 fp16
__device__ __forceinline__ void cvt8(float4 a, float4 b, u16* o) {
  o[0] = f2h(a.x); o[1] = f2h(a.y); o[2] = f2h(a.z); o[3] = f2h(a.w);
  o[4] = f2h(b.x); o[5] = f2h(b.y); o[6] = f2h(b.z); o[7] = f2h(b.w);
}

// (a0,a1) + (c0,c1) elementwise -> 8 fp16
__device__ __forceinline__ void addcvt8(float4 a0, float4 a1, float4 c0, float4 c1, u16* o) {
  o[0] = f2h(a0.x + c0.x); o[1] = f2h(a0.y + c0.y); o[2] = f2h(a0.z + c0.z); o[3] = f2h(a0.w + c0.w);
  o[4] = f2h(a1.x + c1.x); o[5] = f2h(a1.y + c1.y); o[6] = f2h(a1.z + c1.z); o[7] = f2h(a1.w + c1.w);
}

// async global->LDS 16B direct load. LDS dest wave-uniform base; HW adds lane*16.
__device__ __forceinline__ void glds16(const u16* g, u16* l) {
  __builtin_amdgcn_global_load_lds(
      reinterpret_cast<const __attribute__((address_space(1))) u32*>(reinterpret_cast<u64>(g)),
      reinterpret_cast<__attribute__((address_space(3))) u32*>(reinterpret_cast<u64>(l)),
      16, 0, 0);
}

// ---------------------------------------------------------------------------
// Counted-vmcnt pipelined NT tile core (r6 version, unchanged).
// ---------------------------------------------------------------------------
template<int TM, int TN, int WM, int WN, int DEPTH>
__device__ __forceinline__ void gemm_core(const u16* __restrict__ A, int lda,
                                          const u16* __restrict__ B, int ldb,
                                          int ksteps, u16* sA, u16* sB, f32x4 acc[TM][TN]) {
  constexpr int NT = WM * WN * 64;
  constexpr int BM = WM * TM * 16, BN = WN * TN * 16;
  constexpr int TILEA = BM * 32, TILEB = BN * 32;   // u16 per buffer
  constexpr int APF = (BM * 4) / NT, BPF = (BN * 4) / NT;  // glds/thread
  constexpr int VPI = APF + BPF;                    // vmem issued per iter
  constexpr int PF = DEPTH - 2;                     // prefetch depth
  static_assert(PF == 1 || PF == 2, "");
  static_assert(APF >= 1 && BPF >= 1, "");

  const int t = threadIdx.x;
  const int lane = t & 63, wave = t >> 6;
  const int wm = wave / WN, wn = wave % WN;
  const int m16 = lane & 15, q4 = lane >> 4;

  int aoff[APF], asl[APF];
#pragma unroll
  for (int p = 0; p < APF; ++p) {
    int s = p * NT + t, row = s >> 2;
    int kc = (s & 3) ^ ((row >> 1) & 3);
    aoff[p] = row * lda + kc * 8;
    asl[p] = (p * NT + (wave << 6)) * 8;  // wave-uniform LDS u16 base
  }
  int boff[BPF], bsl[BPF];
#pragma unroll
  for (int p = 0; p < BPF; ++p) {
    int s = p * NT + t, row = s >> 2;
    int kc = (s & 3) ^ ((row >> 1) & 3);
    boff[p] = row * ldb + kc * 8;
    bsl[p] = (p * NT + (wave << 6)) * 8;
  }

  int aro[TM], bro[TN];
#pragma unroll
  for (int i = 0; i < TM; ++i) {
    int row = wm * TM * 16 + i * 16 + m16;
    aro[i] = row * 32 + ((q4 ^ ((row >> 1) & 3)) << 3);
  }
#pragma unroll
  for (int j = 0; j < TN; ++j) {
    int row = wn * TN * 16 + j * 16 + m16;
    bro[j] = row * 32 + ((q4 ^ ((row >> 1) & 3)) << 3);
  }

  // prologue: stage tiles 0..PF-1 into buffers 0..PF-1
#pragma unroll
  for (int j = 0; j < PF; ++j) {
    const u16* Aj = A + j * 32;
    u16* aS = sA + j * TILEA;
#pragma unroll
    for (int p = 0; p < APF; ++p) glds16(Aj + aoff[p], aS + asl[p]);
    const u16* Bj = B + j * 32;
    u16* bS = sB + j * TILEB;
#pragma unroll
    for (int p = 0; p < BPF; ++p) glds16(Bj + boff[p], bS + bsl[p]);
  }

  int cur = 0, stg = PF;
#pragma unroll 1
  for (int kt = 0; kt < ksteps; ++kt) {
    if (kt + PF < ksteps) {
      const u16* An = A + (size_t)(kt + PF) * 32;
      u16* aS = sA + stg * TILEA;
#pragma unroll
      for (int p = 0; p < APF; ++p) glds16(An + aoff[p], aS + asl[p]);
      const u16* Bn = B + (size_t)(kt + PF) * 32;
      u16* bS = sB + stg * TILEB;
#pragma unroll
      for (int p = 0; p < BPF; ++p) glds16(Bn + boff[p], bS + bsl[p]);
    }
    if (PF == 2 && kt + 2 < ksteps)
      asm volatile("s_waitcnt vmcnt(%0)" :: "n"(2 * VPI) : "memory");
    else if (kt + 1 < ksteps)
      asm volatile("s_waitcnt vmcnt(%0)" :: "n"(VPI) : "memory");
    else
      asm volatile("s_waitcnt vmcnt(0)" ::: "memory");
    __builtin_amdgcn_s_barrier();
    __builtin_amdgcn_sched_barrier(0);

    const u16* aR = sA + cur * TILEA;
    const u16* bR = sB + cur * TILEB;
    f16x8 af[TM], bv[TN];
#pragma unroll
    for (int i = 0; i < TM; ++i) af[i] = *(const f16x8*)&aR[aro[i]];
#pragma unroll
    for (int j = 0; j < TN; ++j) bv[j] = *(const f16x8*)&bR[bro[j]];
#pragma unroll
    for (int i = 0; i < TM; ++i)
#pragma unroll
      for (int j = 0; j < TN; ++j)
        acc[i][j] = mfma16(af[i], bv[j], acc[i][j]);

    cur = (cur + 1 == DEPTH) ? 0 : cur + 1;
    stg = (stg + 1 == DEPTH) ? 0 : stg + 1;
  }
}

// Merged prep (r6 version — measured 44 µs; r7's 128-tile variant regressed, reverted).
__global__ __launch_bounds__(256) void prep_all_kernel(const float* __restrict__ x,
                                                       u16* __restrict__ xh, u16* __restrict__ xhT,
                                                       const float* __restrict__ q, u16* __restrict__ qh,
                                                       float* __restrict__ qs,
                                                       const float* __restrict__ vw, u16* __restrict__ vwT,
                                                       const float* __restrict__ kw, u16* __restrict__ kwh,
                                                       float* __restrict__ beta) {
  __shared__ __align__(16) u16 T[2 * 64 * 72];
  int blk = blockIdx.x, t = threadIdx.x;
  if (blk < 512) {
    int nt = blk & 63, b = blk >> 6;
    int s = t & 31;
    int c = (t >> 5) * 8;
    const float* xbase = x + ((size_t)b * 512 + 2 * s) * 4096 + nt * 64 + c;
    int rr = t >> 2, og = t & 3;

    float4 ca0 = *(const float4*)xbase;
    float4 ca1 = *(const float4*)(xbase + 4);
    float4 cb0 = *(const float4*)(xbase + 4096);
    float4 cb1 = *(const float4*)(xbase + 4100);

#pragma unroll 1
    for (int ot = 0; ot < 8; ++ot) {
      float4 na0, na1, nb0, nb1;
      if (ot < 7) {
        const float* np = xbase + (size_t)(ot + 1) * 64 * 4096;
        na0 = *(const float4*)np;
        na1 = *(const float4*)(np + 4);
        nb0 = *(const float4*)(np + 4096);
        nb1 = *(const float4*)(np + 4100);
      }
      u16 r0[8], r1[8];
      cvt8(ca0, ca1, r0);
      cvt8(cb0, cb1, r1);

      u16* xq = xh + ((size_t)b * 512 + ot * 64 + 2 * s) * 4096 + nt * 64 + c;
      *(int4*)xq = *(int4*)r0;
      *(int4*)(xq + 4096) = *(int4*)r1;

      u32* Tw = (u32*)(T + (ot & 1) * 4608);
#pragma unroll
      for (int e = 0; e < 8; ++e)
        Tw[(c + e) * 36 + s] = (u32)r0[e] | ((u32)r1[e] << 16);
      __syncthreads();

      const u16* Tr = T + (ot & 1) * 4608;
      int4 v0 = *(const int4*)&Tr[rr * 72 + og * 16];
      int4 v1 = *(const int4*)&Tr[rr * 72 + og * 16 + 8];
      u16* xo = xhT + ((size_t)b * 4096 + nt * 64 + rr) * 512 + ot * 64 + og * 16;
      *(int4*)xo = v0;
      *(int4*)(xo + 8) = v1;

      ca0 = na0; ca1 = na1; cb0 = nb0; cb1 = nb1;
    }
  } else if (blk < 1024) {
    int row = blk - 512;
    float s = 0.f;
#pragma unroll
    for (int p = 0; p < 2; ++p) {
      size_t i = (size_t)row * 4096 + p * 2048 + t * 8;
      u16 o[8];
      ld8f(q + i, o);
#pragma unroll
      for (int e = 0; e < 8; ++e) s += h2f(o[e]);
      *(int4*)&qh[i] = *(int4*)o;
    }
    for (int off = 32; off; off >>= 1) s += __shfl_xor(s, off);
    __shared__ float wsum[4];
    if ((t & 63) == 0) wsum[t >> 6] = s;
    __syncthreads();
    if (t == 0) qs[row] = wsum[0] + wsum[1] + wsum[2] + wsum[3];
  } else if (blk < 1280) {
    int bi = blk - 1024;
    u16* sT = T;
    int bx = bi & 15, by = bi >> 4;
#pragma unroll
    for (int p = 0; p < 4; ++p) {
      int idx = p * 256 + t; int r = idx >> 5, c = idx & 31;
      sT[r * 33 + c] = f2h(vw[(size_t)(by * 32 + r) * 512 + bx * 32 + c]);
    }
    __syncthreads();
#pragma unroll
    for (int p = 0; p < 4; ++p) {
      int idx = p * 256 + t; int r = idx >> 5, c = idx & 31;
      vwT[(size_t)(bx * 32 + r) * 512 + by * 32 + c] = sT[c * 33 + r];
    }
  } else if (blk < 1408) {
    size_t i = ((size_t)(blk - 1280) * 256 + t) * 8;
    u16 o[8];
    ld8f(kw + i, o);
    *(int4*)&kwh[i] = *(int4*)o;
  } else {
    for (int i = t; i < 4096; i += 256) beta[i] = 0.f;
  }
}

// sgemm split-K (r6 version): 128x128 tiles, split-2 over K -> 256 blocks.
__global__ __launch_bounds__(256) void sgemm_kernel(const u16* __restrict__ qh, const u16* __restrict__ xh,
                                                    float* __restrict__ Sp0, float* __restrict__ Sp1) {
  __shared__ __align__(16) u16 sA[4 * 128 * 32], sB[4 * 128 * 32];
  int rt = blockIdx.x, jt = blockIdx.y, ks = blockIdx.z;
  int b = rt >> 2, o0 = (rt & 3) * 128;
  f32x4 acc[4][4];
#pragma unroll
  for (int i = 0; i < 4; ++i)
#pragma unroll
    for (int j = 0; j < 4; ++j) acc[i][j] = (f32x4){0.f, 0.f, 0.f, 0.f};
  gemm_core<4, 4, 2, 2, 4>(qh + (size_t)jt * 128 * 4096 + (size_t)ks * 2048, 4096,
                           xh + ((size_t)b * 512 + o0) * 4096 + (size_t)ks * 2048, 4096,
                           64, sA, sB, acc);

  const int t = threadIdx.x, lane = t & 63, wave = t >> 6;
  const int wm = wave >> 1, wn = wave & 1, m16 = lane & 15, q4 = lane >> 4;
  float* Sp = ks ? Sp1 : Sp0;
  float* Ob = Sp + (size_t)b * 262144;
#pragma unroll
  for (int i = 0; i < 4; ++i)
#pragma unroll
    for (int j = 0; j < 4; ++j)
#pragma unroll
      for (int r2 = 0; r2 < 4; ++r2) {
        int y = jt * 128 + wm * 64 + i * 16 + q4 * 4 + r2;
        int o = o0 + wn * 64 + j * 16 + m16;
        Ob[(size_t)y * 512 + o] = acc[i][j][r2];
      }
}

// Fused egemm + split-K reduce:
// E[b,x,y] = sum_o kwh[x,o] * (Sp0+Sp1)[b,y,o].
// A (kwh 64x512 strip) LDS-RESIDENT: staged once via 16 glds16 (64 KB).
// B reg-staged: fp32 loads from Sp0/Sp1 (2-tile-deep), add+cvt, linear
// conflict-free ds_write_b128 into 3 rotating 4KB buffers (write target
// (kt+1)%3 never collides with laggard reads kt%3 / (kt-1)%3).
__global__ __launch_bounds__(256) void egemm_kernel(const u16* __restrict__ kwh,
                                                    const float* __restrict__ Sp0,
                                                    const float* __restrict__ Sp1,
                                                    float* __restrict__ E) {
  __shared__ __align__(16) u16 sA[16 * 2048];  // resident A, 64 KB, k-swizzled tiles
  __shared__ __align__(16) u16 sB[3 * 2048];   // B stream, 12 KB
  int xt = blockIdx.x >> 3, yt = blockIdx.x & 7, b = blockIdx.y;
  const int t = threadIdx.x, lane = t & 63, wave = t >> 6;
  const int wm = wave >> 1, wn = wave & 1, m16 = lane & 15, q4 = lane >> 4;

  // A: stage all 16 k-tiles (slot s=t -> row=s>>2, swizzled chunk)
  {
    int row = t >> 2;
    int kc = (t & 3) ^ ((row >> 1) & 3);
    const u16* Abase = kwh + (size_t)(xt * 64 + row) * 512 + kc * 8;
    u16* adst = sA + (t & 192) * 8;
#pragma unroll
    for (int k2 = 0; k2 < 16; ++k2)
      glds16(Abase + k2 * 32, adst + k2 * 2048);
  }

  // B source addressing (same swizzle; fp32)
  int srow = t >> 2;
  int skc = (t & 3) ^ ((srow >> 1) & 3);
  const float* b0 = Sp0 + (size_t)b * 262144 + (size_t)(yt * 64 + srow) * 512 + skc * 8;
  const float* b1 = Sp1 + (size_t)b * 262144 + (size_t)(yt * 64 + srow) * 512 + skc * 8;

  // two register groups (even/odd tiles), all statically indexed
  float4 pa0, pa1, pa2, pa3, pb0, pb1, pb2, pb3;
  pa0 = *(const float4*)(b0);      pa1 = *(const float4*)(b0 + 4);
  pa2 = *(const float4*)(b1);      pa3 = *(const float4*)(b1 + 4);
  pb0 = *(const float4*)(b0 + 32); pb1 = *(const float4*)(b0 + 36);
  pb2 = *(const float4*)(b1 + 32); pb3 = *(const float4*)(b1 + 36);
  {
    u16 h[8];
    addcvt8(pa0, pa1, pa2, pa3, h);            // tile 0
    *(int4*)&sB[t * 8] = *(int4*)h;
  }
  asm volatile("s_waitcnt vmcnt(0) lgkmcnt(0)" ::: "memory");
  __builtin_amdgcn_s_barrier();

  int aro[2], bro[2];
#pragma unroll
  for (int i = 0; i < 2; ++i) {
    int row = wm * 32 + i * 16 + m16;
    aro[i] = row * 32 + ((q4 ^ ((row >> 1) & 3)) << 3);
  }
#pragma unroll
  for (int j = 0; j < 2; ++j) {
    int row = wn * 32 + j * 16 + m16;
    bro[j] = row * 32 + ((q4 ^ ((row >> 1) & 3)) << 3);
  }

  f32x4 acc[2][2];
#pragma unroll
  for (int i = 0; i < 2; ++i)
#pragma unroll
    for (int j = 0; j < 2; ++j) acc[i][j] = (f32x4){0.f, 0.f, 0.f, 0.f};

#pragma unroll 2
  for (int kt = 0; kt < 16; ++kt) {
    if (kt + 2 < 16) {  // load tile kt+2 into group (kt&1)
      const float* s0 = b0 + (kt + 2) * 32;
      const float* s1 = b1 + (kt + 2) * 32;
      if (kt & 1) {
        pb0 = *(const float4*)s0; pb1 = *(const float4*)(s0 + 4);
        pb2 = *(const float4*)s1; pb3 = *(const float4*)(s1 + 4);
      } else {
        pa0 = *(const float4*)s0; pa1 = *(const float4*)(s0 + 4);
        pa2 = *(const float4*)s1; pa3 = *(const float4*)(s1 + 4);
      }
    }
    if (kt + 1 < 16) {  // cvt+write tile kt+1 from group ((kt+1)&1)
      u16 h[8];
      if (kt & 1) addcvt8(pa0, pa1, pa2, pa3, h);
      else        addcvt8(pb0, pb1, pb2, pb3, h);
      *(int4*)&sB[((kt + 1) % 3) * 2048 + t * 8] = *(int4*)h;
    }
    asm volatile("s_waitcnt lgkmcnt(0)" ::: "memory");
    __builtin_amdgcn_s_barrier();
    __builtin_amdgcn_sched_barrier(0);

    const u16* aT = sA + kt * 2048;
    const u16* bT = sB + (kt % 3) * 2048;
    f16x8 af[2], bv[2];
#pragma unroll
    for (int i = 0; i < 2; ++i) af[i] = *(const f16x8*)&aT[aro[i]];
#pragma unroll
    for (int j = 0; j < 2; ++j) bv[j] = *(const f16x8*)&bT[bro[j]];
#pragma unroll
    for (int i = 0; i < 2; ++i)
#pragma unroll
      for (int j = 0; j < 2; ++j)
        acc[i][j] = mfma16(af[i], bv[j], acc[i][j]);
  }

  float* O = E + ((size_t)b * 512 + xt * 64) * 512 + yt * 64;
#pragma unroll
  for (int i = 0; i < 2; ++i)
#pragma unroll
    for (int j = 0; j < 2; ++j)
#pragma unroll
      for (int r2 = 0; r2 < 4; ++r2) {
        int row = wm * 32 + i * 16 + q4 * 4 + r2;
        int col = wn * 32 + j * 16 + m16;
        O[(size_t)row * 512 + col] = acc[i][j][r2];
      }
}

// softmax over y of (E[b,x,y]+kb[x]*qs[y]); writes attT fp16; beta += sum_x att*vb[x]
__global__ __launch_bounds__(256) void softmax_kernel(const float* __restrict__ E, const float* __restrict__ qs,
                                                      const float* __restrict__ kb, const float* __restrict__ vb,
                                                      u16* __restrict__ attT, float* __restrict__ beta) {
  __shared__ float sE[16 * 516];
  __shared__ float sM[16], sS[16];
  int i0 = blockIdx.x * 16, b = blockIdx.y, t = threadIdx.x;
  const float* Eb = E + ((size_t)b * 512 + i0) * 512;
  for (int ch = 0; ch < 32; ++ch) {
    int idx = ch * 256 + t;
    int row = idx >> 9, col = idx & 511;
    sE[row * 516 + col] = Eb[(size_t)row * 512 + col] + kb[i0 + row] * qs[col];
  }
  __syncthreads();
  {
    int row = t >> 4, sub = t & 15;
    float mx = -1e30f;
    for (int ii = 0; ii < 32; ++ii) mx = fmaxf(mx, sE[row * 516 + sub + ii * 16]);
    for (int off = 8; off; off >>= 1) mx = fmaxf(mx, __shfl_xor(mx, off));
    float sm = 0.f;
    for (int ii = 0; ii < 32; ++ii) sm += __expf(sE[row * 516 + sub + ii * 16] - mx);
    for (int off = 8; off; off >>= 1) sm += __shfl_xor(sm, off);
    if (sub == 0) { sM[row] = mx; sS[row] = 1.f / sm; }
  }
  __syncthreads();
  float vbr = vb[i0 + (t & 15)];
  u16* Ob = attT + (size_t)b * 262144;
  for (int ch = 0; ch < 32; ++ch) {
    int idx = ch * 256 + t;
    int r = idx & 15, j = idx >> 4;
    float a = __expf(sE[r * 516 + j] - sM[r]) * sS[r];
    Ob[(size_t)j * 512 + i0 + r] = f2h(a);
    float part = a * vbr;
    for (int off = 8; off; off >>= 1) part += __shfl_xor(part, off);
    if (r == 0) atomicAdd(&beta[b * 512 + j], part);
  }
}

// W[b][c][o] = sum_x attT[b][c][x] * vwT[o][x] (r6 version)
__global__ __launch_bounds__(256) void wgemm_kernel(const u16* __restrict__ attT, const u16* __restrict__ vwT,
                                                    u16* __restrict__ W) {
  __shared__ __align__(16) u16 sA[4 * 64 * 32], sB[4 * 64 * 32];
  int ct = blockIdx.x >> 3, ot = blockIdx.x & 7, b = blockIdx.y;
  f32x4 acc[2][2];
#pragma unroll
  for (int i = 0; i < 2; ++i)
#pragma unroll
    for (int j = 0; j < 2; ++j) acc[i][j] = (f32x4){0.f, 0.f, 0.f, 0.f};
  gemm_core<2, 2, 2, 2, 4>(attT + (size_t)b * 262144 + (size_t)ct * 64 * 512, 512,
                           vwT + (size_t)ot * 64 * 512, 512, 16, sA, sB, acc);

  const int t = threadIdx.x, lane = t & 63, wave = t >> 6;
  const int wm = wave >> 1, wn = wave & 1, m16 = lane & 15, q4 = lane >> 4;
  u16* O = W + (size_t)b * 262144 + (size_t)(ct * 64) * 512 + ot * 64;
#pragma unroll
  for (int i = 0; i < 2; ++i)
#pragma unroll
    for (int j = 0; j < 2; ++j)
#pragma unroll
      for (int r2 = 0; r2 < 4; ++r2) {
        int row = wm * 32 + i * 16 + q4 * 4 + r2;
        int col = wn * 32 + j * 16 + m16;
        O[(size_t)row * 512 + col] = f2h(acc[i][j][r2]);
      }
}

// out = gamma*(W·xhT + beta) + x (r6 version)
__global__ __launch_bounds__(256) void outgemm_kernel(const u16* __restrict__ W, const u16* __restrict__ xhT,
                                                      const float* __restrict__ x, const float* __restrict__ beta,
                                                      const float* __restrict__ gm, float* __restrict__ out) {
  __shared__ __align__(16) u16 sA[4 * 128 * 32], sB[4 * 128 * 32];
  int nt = blockIdx.x, ct = blockIdx.y, b = blockIdx.z;
  f32x4 acc[4][4];
#pragma unroll
  for (int i = 0; i < 4; ++i)
#pragma unroll
    for (int j = 0; j < 4; ++j) acc[i][j] = (f32x4){0.f, 0.f, 0.f, 0.f};
  gemm_core<4, 4, 2, 2, 4>(W + (size_t)b * 262144 + (size_t)ct * 128 * 512, 512,
                           xhT + (size_t)b * 2097152 + (size_t)nt * 128 * 512, 512, 16, sA, sB, acc);

  const int t = threadIdx.x, lane = t & 63, wave = t >> 6;
  const int wm = wave >> 1, wn = wave & 1, m16 = lane & 15, q4 = lane >> 4;
  float g = gm[0];
#pragma unroll
  for (int i = 0; i < 4; ++i)
#pragma unroll
    for (int j = 0; j < 4; ++j)
#pragma unroll
      for (int r2 = 0; r2 < 4; ++r2) {
        int c = ct * 128 + wm * 64 + i * 16 + q4 * 4 + r2;
        int n = nt * 128 + wn * 64 + j * 16 + m16;
        size_t idx = (size_t)b * 2097152 + (size_t)c * 4096 + n;
        out[idx] = g * (acc[i][j][r2] + beta[b * 512 + c]) + x[idx];
      }
}

extern "C" void kernel_launch(void* const* d_in, const int* in_sizes, int n_in,
                              void* d_out, int out_size, void* d_ws, size_t ws_size,
                              hipStream_t stream) {
  const float* x  = (const float*)d_in[0];
  const float* pq = (const float*)d_in[1];
  const float* kw = (const float*)d_in[2];
  const float* kb = (const float*)d_in[3];
  const float* vw = (const float*)d_in[4];
  const float* vb = (const float*)d_in[5];
  const float* gm = (const float*)d_in[6];
  float* out = (float*)d_out;

  // workspace: 94 MB
  char* ws = (char*)d_ws;
  u16*   xh   = (u16*)(ws);                            // [0,32M)  fp16 x [b][o][n]
  u16*   qh   = (u16*)(ws + (32ull << 20));            // [32,36M) dead after sgemm
  float* E    = (float*)(ws + (32ull << 20));          // [32,40M) fp32, live egemm->softmax
  u16*   W    = (u16*)(ws + (36ull << 20));            // [36,40M) live wgemm->outgemm (E dead by then)
  float* Sp0  = (float*)(ws + (40ull << 20));          // [40,48M) split-K partial 0
  u16*   attT = (u16*)(ws + (48ull << 20));            // [48,52M)
  u16*   kwh  = (u16*)(ws + (52ull << 20));            // 512K
  u16*   vwT  = (u16*)(ws + (52ull << 20) + 524288);   // 512K
  char*  sm   = ws + (53ull << 20);                    // small region
  float* qs   = (float*)(sm);
  float* beta = (float*)(sm + 4096);                   // 16K
  u16*   xhT  = (u16*)(ws + (54ull << 20));            // [54,86M) fp16 x^T [b][n][o]
  float* Sp1  = (float*)(ws + (86ull << 20));          // [86,94M) split-K partial 1

  prep_all_kernel<<<dim3(1409), 256, 0, stream>>>(x, xh, xhT, pq, qh, qs, vw, vwT, kw, kwh, beta);
  sgemm_kernel<<<dim3(32, 4, 2), 256, 0, stream>>>(qh, xh, Sp0, Sp1);
  egemm_kernel<<<dim3(64, 8), 256, 0, stream>>>(kwh, Sp0, Sp1, E);
  softmax_kernel<<<dim3(32, 8), 256, 0, stream>>>(E, qs, kb, vb, attT, beta);
  wgemm_kernel<<<dim3(64, 8), 256, 0, stream>>>(attT, vwT, W);
  outgemm_kernel<<<dim3(32, 4, 8), 256, 0, stream>>>(W, xhT, x, beta, gm, out);
}

// Round 9
// 239.961 us; speedup vs baseline: 1.0387x; 1.0097x over previous
//
#include <hip/hip_runtime.h>

typedef unsigned short u16;
typedef unsigned int u32;
typedef unsigned long long u64;
typedef _Float16 f16x8 __attribute__((ext_vector_type(8)));
typedef float f32x4 __attribute__((ext_vector_type(4)));

__device__ __forceinline__ u16 f2h(float f) {
  union { _Float16 h; u16 u; } c; c.h = (_Float16)f; return c.u;
}
__device__ __forceinline__ float h2f(u16 v) {
  union { u16 u; _Float16 h; } c; c.u = v; return (float)c.h;
}

__device__ __forceinline__ f32x4 mfma16(f16x8 a, f16x8 b, f32x4 c) {
  return __builtin_amdgcn_mfma_f32_16x16x32_f16(a, b, c, 0, 0, 0);
}

// 8 contiguous fp32 -> 8 fp16 (u16)
__device__ __forceinline__ void ld8f(const float* s, u16* o) {
  float4 a = *(const float4*)s;
  float4 b = *(const float4*)(s + 4);
  o[0] = f2h(a.x); o[1] = f2h(a.y); o[2] = f2h(a.z); o[3] = f2h(a.w);
  o[4] = f2h(b.x); o[5] = f2h(b.y); o[6] = f2h(b.z); o[7] = f2h(b.w);
}

// pack two float4-pairs (8 floats) to 8 fp16
__device__ __forceinline__ void cvt8(float4 a, float4 b, u16* o) {
  o[0] = f2h(a.x); o[1] = f2h(a.y); o[2] = f2h(a.z); o[3] = f2h(a.w);
  o[4] = f2h(b.x); o[5] = f2h(b.y); o[6] = f2h(b.z); o[7] = f2h(b.w);
}

// (a0,a1) + (c0,c1) elementwise -> 8 fp16
__device__ __forceinline__ void addcvt8(float4 a0, float4 a1, float4 c0, float4 c1, u16* o) {
  o[0] = f2h(a0.x + c0.x); o[1] = f2h(a0.y + c0.y); o[2] = f2h(a0.z + c0.z); o[3] = f2h(a0.w + c0.w);
  o[4] = f2h(a1.x + c1.x); o[5] = f2h(a1.y + c1.y); o[6] = f2h(a1.z + c1.z); o[7] = f2h(a1.w + c1.w);
}

// async global->LDS 16B direct load. LDS dest wave-uniform base; HW adds lane*16.
__device__ __forceinline__ void glds16(const u16* g, u16* l) {
  __builtin_amdgcn_global_load_lds(
      reinterpret_cast<const __attribute__((address_space(1))) u32*>(reinterpret_cast<u64>(g)),
      reinterpret_cast<__attribute__((address_space(3))) u32*>(reinterpret_cast<u64>(l)),
      16, 0, 0);
}

// ---------------------------------------------------------------------------
// Counted-vmcnt pipelined NT tile core (unchanged).
// ---------------------------------------------------------------------------
template<int TM, int TN, int WM, int WN, int DEPTH>
__device__ __forceinline__ void gemm_core(const u16* __restrict__ A, int lda,
                                          const u16* __restrict__ B, int ldb,
                                          int ksteps, u16* sA, u16* sB, f32x4 acc[TM][TN]) {
  constexpr int NT = WM * WN * 64;
  constexpr int BM = WM * TM * 16, BN = WN * TN * 16;
  constexpr int TILEA = BM * 32, TILEB = BN * 32;   // u16 per buffer
  constexpr int APF = (BM * 4) / NT, BPF = (BN * 4) / NT;  // glds/thread
  constexpr int VPI = APF + BPF;                    // vmem issued per iter
  constexpr int PF = DEPTH - 2;                     // prefetch depth
  static_assert(PF == 1 || PF == 2, "");
  static_assert(APF >= 1 && BPF >= 1, "");

  const int t = threadIdx.x;
  const int lane = t & 63, wave = t >> 6;
  const int wm = wave / WN, wn = wave % WN;
  const int m16 = lane & 15, q4 = lane >> 4;

  int aoff[APF], asl[APF];
#pragma unroll
  for (int p = 0; p < APF; ++p) {
    int s = p * NT + t, row = s >> 2;
    int kc = (s & 3) ^ ((row >> 1) & 3);
    aoff[p] = row * lda + kc * 8;
    asl[p] = (p * NT + (wave << 6)) * 8;  // wave-uniform LDS u16 base
  }
  int boff[BPF], bsl[BPF];
#pragma unroll
  for (int p = 0; p < BPF; ++p) {
    int s = p * NT + t, row = s >> 2;
    int kc = (s & 3) ^ ((row >> 1) & 3);
    boff[p] = row * ldb + kc * 8;
    bsl[p] = (p * NT + (wave << 6)) * 8;
  }

  int aro[TM], bro[TN];
#pragma unroll
  for (int i = 0; i < TM; ++i) {
    int row = wm * TM * 16 + i * 16 + m16;
    aro[i] = row * 32 + ((q4 ^ ((row >> 1) & 3)) << 3);
  }
#pragma unroll
  for (int j = 0; j < TN; ++j) {
    int row = wn * TN * 16 + j * 16 + m16;
    bro[j] = row * 32 + ((q4 ^ ((row >> 1) & 3)) << 3);
  }

  // prologue: stage tiles 0..PF-1 into buffers 0..PF-1
#pragma unroll
  for (int j = 0; j < PF; ++j) {
    const u16* Aj = A + j * 32;
    u16* aS = sA + j * TILEA;
#pragma unroll
    for (int p = 0; p < APF; ++p) glds16(Aj + aoff[p], aS + asl[p]);
    const u16* Bj = B + j * 32;
    u16* bS = sB + j * TILEB;
#pragma unroll
    for (int p = 0; p < BPF; ++p) glds16(Bj + boff[p], bS + bsl[p]);
  }

  int cur = 0, stg = PF;
#pragma unroll 1
  for (int kt = 0; kt < ksteps; ++kt) {
    if (kt + PF < ksteps) {
      const u16* An = A + (size_t)(kt + PF) * 32;
      u16* aS = sA + stg * TILEA;
#pragma unroll
      for (int p = 0; p < APF; ++p) glds16(An + aoff[p], aS + asl[p]);
      const u16* Bn = B + (size_t)(kt + PF) * 32;
      u16* bS = sB + stg * TILEB;
#pragma unroll
      for (int p = 0; p < BPF; ++p) glds16(Bn + boff[p], bS + bsl[p]);
    }
    if (PF == 2 && kt + 2 < ksteps)
      asm volatile("s_waitcnt vmcnt(%0)" :: "n"(2 * VPI) : "memory");
    else if (kt + 1 < ksteps)
      asm volatile("s_waitcnt vmcnt(%0)" :: "n"(VPI) : "memory");
    else
      asm volatile("s_waitcnt vmcnt(0)" ::: "memory");
    __builtin_amdgcn_s_barrier();
    __builtin_amdgcn_sched_barrier(0);

    const u16* aR = sA + cur * TILEA;
    const u16* bR = sB + cur * TILEB;
    f16x8 af[TM], bv[TN];
#pragma unroll
    for (int i = 0; i < TM; ++i) af[i] = *(const f16x8*)&aR[aro[i]];
#pragma unroll
    for (int j = 0; j < TN; ++j) bv[j] = *(const f16x8*)&bR[bro[j]];
#pragma unroll
    for (int i = 0; i < TM; ++i)
#pragma unroll
      for (int j = 0; j < TN; ++j)
        acc[i][j] = mfma16(af[i], bv[j], acc[i][j]);

    cur = (cur + 1 == DEPTH) ? 0 : cur + 1;
    stg = (stg + 1 == DEPTH) ? 0 : stg + 1;
  }
}

// ---------------------------------------------------------------------------
// Merged prep.
// x-role blocks [0,512): block = (b, nt 64-n strip). NEW: full 64x512 slab
//   buffered in LDS (stride-257 u32: phase-1 writes (c+e+s)&31 2-way free;
//   phase-2 b32 reads (n+4i)&31 2-way free), then xhT written DENSE: every
//   row a full 1 KB, 64 KB contiguous block region per block. Tests the
//   write-stream-density theory of prep's 2.5 TB/s cap. One barrier total.
// [512,1024): q rows; [1024,1280): vwT; [1280,1408): kwh; 1408: beta=0.
// ---------------------------------------------------------------------------
__global__ __launch_bounds__(256) void prep_all_kernel(const float* __restrict__ x,
                                                       u16* __restrict__ xh, u16* __restrict__ xhT,
                                                       const float* __restrict__ q, u16* __restrict__ qh,
                                                       float* __restrict__ qs,
                                                       const float* __restrict__ vw, u16* __restrict__ vwT,
                                                       const float* __restrict__ kw, u16* __restrict__ kwh,
                                                       float* __restrict__ beta) {
  __shared__ __align__(16) u32 TS[64 * 257];  // 65792 B
  int blk = blockIdx.x, t = threadIdx.x;
  if (blk < 512) {
    int nt = blk & 63, b = blk >> 6;
    int s = t & 31;        // o-pair index (o_local = 2s, 2s+1)
    int c = (t >> 5) * 8;  // n_local base
    const float* xbase = x + ((size_t)b * 512 + 2 * s) * 4096 + nt * 64 + c;

    float4 ca0 = *(const float4*)xbase;
    float4 ca1 = *(const float4*)(xbase + 4);
    float4 cb0 = *(const float4*)(xbase + 4096);
    float4 cb1 = *(const float4*)(xbase + 4100);

#pragma unroll 1
    for (int ot = 0; ot < 8; ++ot) {
      float4 na0, na1, nb0, nb1;
      if (ot < 7) {
        const float* np = xbase + (size_t)(ot + 1) * 64 * 4096;
        na0 = *(const float4*)np;
        na1 = *(const float4*)(np + 4);
        nb0 = *(const float4*)(np + 4096);
        nb1 = *(const float4*)(np + 4100);
      }
      u16 r0[8], r1[8];
      cvt8(ca0, ca1, r0);
      cvt8(cb0, cb1, r1);

      // xh pass-through (coalesced)
      u16* xq = xh + ((size_t)b * 512 + ot * 64 + 2 * s) * 4096 + nt * 64 + c;
      *(int4*)xq = *(int4*)r0;
      *(int4*)(xq + 4096) = *(int4*)r1;

      // accumulate transposed slab: TS[n_local][opair], no per-iter barrier
#pragma unroll
      for (int e = 0; e < 8; ++e)
        TS[(c + e) * 257 + ot * 32 + s] = (u32)r0[e] | ((u32)r1[e] << 16);

      ca0 = na0; ca1 = na1; cb0 = nb0; cb1 = nb1;
    }
    __syncthreads();

    // phase 2: dense write-out. lane = row n (2-way free b32 reads),
    // block writes its full 64 KB xhT region densely.
    int n = t & 63, w = t >> 6;
    const u32* Trow = TS + n * 257 + w * 64;
    u16* xo = xhT + ((size_t)b * 4096 + nt * 64 + n) * 512 + w * 128;
#pragma unroll
    for (int i = 0; i < 16; ++i) {
      u32 vv[4];
      vv[0] = Trow[4 * i]; vv[1] = Trow[4 * i + 1];
      vv[2] = Trow[4 * i + 2]; vv[3] = Trow[4 * i + 3];
      *(int4*)(xo + 8 * i) = *(int4*)vv;
    }
  } else if (blk < 1024) {
    int row = blk - 512;
    float s = 0.f;
#pragma unroll
    for (int p = 0; p < 2; ++p) {
      size_t i = (size_t)row * 4096 + p * 2048 + t * 8;
      u16 o[8];
      ld8f(q + i, o);
#pragma unroll
      for (int e = 0; e < 8; ++e) s += h2f(o[e]);
      *(int4*)&qh[i] = *(int4*)o;
    }
    for (int off = 32; off; off >>= 1) s += __shfl_xor(s, off);
    __shared__ float wsum[4];
    if ((t & 63) == 0) wsum[t >> 6] = s;
    __syncthreads();
    if (t == 0) qs[row] = wsum[0] + wsum[1] + wsum[2] + wsum[3];
  } else if (blk < 1280) {
    int bi = blk - 1024;
    u16* sT = (u16*)TS;  // reuse (needs 32*33 u16)
    int bx = bi & 15, by = bi >> 4;
#pragma unroll
    for (int p = 0; p < 4; ++p) {
      int idx = p * 256 + t; int r = idx >> 5, c = idx & 31;
      sT[r * 33 + c] = f2h(vw[(size_t)(by * 32 + r) * 512 + bx * 32 + c]);
    }
    __syncthreads();
#pragma unroll
    for (int p = 0; p < 4; ++p) {
      int idx = p * 256 + t; int r = idx >> 5, c = idx & 31;
      vwT[(size_t)(bx * 32 + r) * 512 + by * 32 + c] = sT[c * 33 + r];
    }
  } else if (blk < 1408) {
    size_t i = ((size_t)(blk - 1280) * 256 + t) * 8;
    u16 o[8];
    ld8f(kw + i, o);
    *(int4*)&kwh[i] = *(int4*)o;
  } else {
    for (int i = t; i < 4096; i += 256) beta[i] = 0.f;
  }
}

// sgemm split-K: 128x128 tiles, split-2 over K -> 256 blocks.
__global__ __launch_bounds__(256) void sgemm_kernel(const u16* __restrict__ qh, const u16* __restrict__ xh,
                                                    float* __restrict__ Sp0, float* __restrict__ Sp1) {
  __shared__ __align__(16) u16 sA[4 * 128 * 32], sB[4 * 128 * 32];
  int rt = blockIdx.x, jt = blockIdx.y, ks = blockIdx.z;
  int b = rt >> 2, o0 = (rt & 3) * 128;
  f32x4 acc[4][4];
#pragma unroll
  for (int i = 0; i < 4; ++i)
#pragma unroll
    for (int j = 0; j < 4; ++j) acc[i][j] = (f32x4){0.f, 0.f, 0.f, 0.f};
  gemm_core<4, 4, 2, 2, 4>(qh + (size_t)jt * 128 * 4096 + (size_t)ks * 2048, 4096,
                           xh + ((size_t)b * 512 + o0) * 4096 + (size_t)ks * 2048, 4096,
                           64, sA, sB, acc);

  const int t = threadIdx.x, lane = t & 63, wave = t >> 6;
  const int wm = wave >> 1, wn = wave & 1, m16 = lane & 15, q4 = lane >> 4;
  float* Sp = ks ? Sp1 : Sp0;
  float* Ob = Sp + (size_t)b * 262144;
#pragma unroll
  for (int i = 0; i < 4; ++i)
#pragma unroll
    for (int j = 0; j < 4; ++j)
#pragma unroll
      for (int r2 = 0; r2 < 4; ++r2) {
        int y = jt * 128 + wm * 64 + i * 16 + q4 * 4 + r2;
        int o = o0 + wn * 64 + j * 16 + m16;
        Ob[(size_t)y * 512 + o] = acc[i][j][r2];
      }
}

// Fused egemm + split-K reduce (r8 version).
__global__ __launch_bounds__(256) void egemm_kernel(const u16* __restrict__ kwh,
                                                    const float* __restrict__ Sp0,
                                                    const float* __restrict__ Sp1,
                                                    float* __restrict__ E) {
  __shared__ __align__(16) u16 sA[16 * 2048];  // resident A, 64 KB
  __shared__ __align__(16) u16 sB[3 * 2048];   // B stream, 12 KB
  int xt = blockIdx.x >> 3, yt = blockIdx.x & 7, b = blockIdx.y;
  const int t = threadIdx.x, lane = t & 63, wave = t >> 6;
  const int wm = wave >> 1, wn = wave & 1, m16 = lane & 15, q4 = lane >> 4;

  {
    int row = t >> 2;
    int kc = (t & 3) ^ ((row >> 1) & 3);
    const u16* Abase = kwh + (size_t)(xt * 64 + row) * 512 + kc * 8;
    u16* adst = sA + (t & 192) * 8;
#pragma unroll
    for (int k2 = 0; k2 < 16; ++k2)
      glds16(Abase + k2 * 32, adst + k2 * 2048);
  }

  int srow = t >> 2;
  int skc = (t & 3) ^ ((srow >> 1) & 3);
  const float* b0 = Sp0 + (size_t)b * 262144 + (size_t)(yt * 64 + srow) * 512 + skc * 8;
  const float* b1 = Sp1 + (size_t)b * 262144 + (size_t)(yt * 64 + srow) * 512 + skc * 8;

  float4 pa0, pa1, pa2, pa3, pb0, pb1, pb2, pb3;
  pa0 = *(const float4*)(b0);      pa1 = *(const float4*)(b0 + 4);
  pa2 = *(const float4*)(b1);      pa3 = *(const float4*)(b1 + 4);
  pb0 = *(const float4*)(b0 + 32); pb1 = *(const float4*)(b0 + 36);
  pb2 = *(const float4*)(b1 + 32); pb3 = *(const float4*)(b1 + 36);
  {
    u16 h[8];
    addcvt8(pa0, pa1, pa2, pa3, h);            // tile 0
    *(int4*)&sB[t * 8] = *(int4*)h;
  }
  asm volatile("s_waitcnt vmcnt(0) lgkmcnt(0)" ::: "memory");
  __builtin_amdgcn_s_barrier();

  int aro[2], bro[2];
#pragma unroll
  for (int i = 0; i < 2; ++i) {
    int row = wm * 32 + i * 16 + m16;
    aro[i] = row * 32 + ((q4 ^ ((row >> 1) & 3)) << 3);
  }
#pragma unroll
  for (int j = 0; j < 2; ++j) {
    int row = wn * 32 + j * 16 + m16;
    bro[j] = row * 32 + ((q4 ^ ((row >> 1) & 3)) << 3);
  }

  f32x4 acc[2][2];
#pragma unroll
  for (int i = 0; i < 2; ++i)
#pragma unroll
    for (int j = 0; j < 2; ++j) acc[i][j] = (f32x4){0.f, 0.f, 0.f, 0.f};

#pragma unroll 2
  for (int kt = 0; kt < 16; ++kt) {
    if (kt + 2 < 16) {
      const float* s0 = b0 + (kt + 2) * 32;
      const float* s1 = b1 + (kt + 2) * 32;
      if (kt & 1) {
        pb0 = *(const float4*)s0; pb1 = *(const float4*)(s0 + 4);
        pb2 = *(const float4*)s1; pb3 = *(const float4*)(s1 + 4);
      } else {
        pa0 = *(const float4*)s0; pa1 = *(const float4*)(s0 + 4);
        pa2 = *(const float4*)s1; pa3 = *(const float4*)(s1 + 4);
      }
    }
    if (kt + 1 < 16) {
      u16 h[8];
      if (kt & 1) addcvt8(pa0, pa1, pa2, pa3, h);
      else        addcvt8(pb0, pb1, pb2, pb3, h);
      *(int4*)&sB[((kt + 1) % 3) * 2048 + t * 8] = *(int4*)h;
    }
    asm volatile("s_waitcnt lgkmcnt(0)" ::: "memory");
    __builtin_amdgcn_s_barrier();
    __builtin_amdgcn_sched_barrier(0);

    const u16* aT = sA + kt * 2048;
    const u16* bT = sB + (kt % 3) * 2048;
    f16x8 af[2], bv[2];
#pragma unroll
    for (int i = 0; i < 2; ++i) af[i] = *(const f16x8*)&aT[aro[i]];
#pragma unroll
    for (int j = 0; j < 2; ++j) bv[j] = *(const f16x8*)&bT[bro[j]];
#pragma unroll
    for (int i = 0; i < 2; ++i)
#pragma unroll
      for (int j = 0; j < 2; ++j)
        acc[i][j] = mfma16(af[i], bv[j], acc[i][j]);
  }

  float* O = E + ((size_t)b * 512 + xt * 64) * 512 + yt * 64;
#pragma unroll
  for (int i = 0; i < 2; ++i)
#pragma unroll
    for (int j = 0; j < 2; ++j)
#pragma unroll
      for (int r2 = 0; r2 < 4; ++r2) {
        int row = wm * 32 + i * 16 + q4 * 4 + r2;
        int col = wn * 32 + j * 16 + m16;
        O[(size_t)row * 512 + col] = acc[i][j][r2];
      }
}

// softmax over y of (E[b,x,y]+kb[x]*qs[y]); writes attT fp16; beta += sum_x att*vb[x]
__global__ __launch_bounds__(256) void softmax_kernel(const float* __restrict__ E, const float* __restrict__ qs,
                                                      const float* __restrict__ kb, const float* __restrict__ vb,
                                                      u16* __restrict__ attT, float* __restrict__ beta) {
  __shared__ float sE[16 * 516];
  __shared__ float sM[16], sS[16];
  int i0 = blockIdx.x * 16, b = blockIdx.y, t = threadIdx.x;
  const float* Eb = E + ((size_t)b * 512 + i0) * 512;
  for (int ch = 0; ch < 32; ++ch) {
    int idx = ch * 256 + t;
    int row = idx >> 9, col = idx & 511;
    sE[row * 516 + col] = Eb[(size_t)row * 512 + col] + kb[i0 + row] * qs[col];
  }
  __syncthreads();
  {
    int row = t >> 4, sub = t & 15;
    float mx = -1e30f;
    for (int ii = 0; ii < 32; ++ii) mx = fmaxf(mx, sE[row * 516 + sub + ii * 16]);
    for (int off = 8; off; off >>= 1) mx = fmaxf(mx, __shfl_xor(mx, off));
    float sm = 0.f;
    for (int ii = 0; ii < 32; ++ii) sm += __expf(sE[row * 516 + sub + ii * 16] - mx);
    for (int off = 8; off; off >>= 1) sm += __shfl_xor(sm, off);
    if (sub == 0) { sM[row] = mx; sS[row] = 1.f / sm; }
  }
  __syncthreads();
  float vbr = vb[i0 + (t & 15)];
  u16* Ob = attT + (size_t)b * 262144;
  for (int ch = 0; ch < 32; ++ch) {
    int idx = ch * 256 + t;
    int r = idx & 15, j = idx >> 4;
    float a = __expf(sE[r * 516 + j] - sM[r]) * sS[r];
    Ob[(size_t)j * 512 + i0 + r] = f2h(a);
    float part = a * vbr;
    for (int off = 8; off; off >>= 1) part += __shfl_xor(part, off);
    if (r == 0) atomicAdd(&beta[b * 512 + j], part);
  }
}

// W[b][c][o] = sum_x attT[b][c][x] * vwT[o][x]
__global__ __launch_bounds__(256) void wgemm_kernel(const u16* __restrict__ attT, const u16* __restrict__ vwT,
                                                    u16* __restrict__ W) {
  __shared__ __align__(16) u16 sA[4 * 64 * 32], sB[4 * 64 * 32];
  int ct = blockIdx.x >> 3, ot = blockIdx.x & 7, b = blockIdx.y;
  f32x4 acc[2][2];
#pragma unroll
  for (int i = 0; i < 2; ++i)
#pragma unroll
    for (int j = 0; j < 2; ++j) acc[i][j] = (f32x4){0.f, 0.f, 0.f, 0.f};
  gemm_core<2, 2, 2, 2, 4>(attT + (size_t)b * 262144 + (size_t)ct * 64 * 512, 512,
                           vwT + (size_t)ot * 64 * 512, 512, 16, sA, sB, acc);

  const int t = threadIdx.x, lane = t & 63, wave = t >> 6;
  const int wm = wave >> 1, wn = wave & 1, m16 = lane & 15, q4 = lane >> 4;
  u16* O = W + (size_t)b * 262144 + (size_t)(ct * 64) * 512 + ot * 64;
#pragma unroll
  for (int i = 0; i < 2; ++i)
#pragma unroll
    for (int j = 0; j < 2; ++j)
#pragma unroll
      for (int r2 = 0; r2 < 4; ++r2) {
        int row = wm * 32 + i * 16 + q4 * 4 + r2;
        int col = wn * 32 + j * 16 + m16;
        O[(size_t)row * 512 + col] = f2h(acc[i][j][r2]);
      }
}

// out = gamma*(W·xhT + beta) + xh  (residual from fp16 xh: -64 MB HBM read;
// rounding <= 2^-11 relative on the residual term, absmax impact ~0.001)
__global__ __launch_bounds__(256) void outgemm_kernel(const u16* __restrict__ W, const u16* __restrict__ xhT,
                                                      const u16* __restrict__ xh, const float* __restrict__ beta,
                                                      const float* __restrict__ gm, float* __restrict__ out) {
  __shared__ __align__(16) u16 sA[4 * 128 * 32], sB[4 * 128 * 32];
  int nt = blockIdx.x, ct = blockIdx.y, b = blockIdx.z;
  f32x4 acc[4][4];
#pragma unroll
  for (int i = 0; i < 4; ++i)
#pragma unroll
    for (int j = 0; j < 4; ++j) acc[i][j] = (f32x4){0.f, 0.f, 0.f, 0.f};
  gemm_core<4, 4, 2, 2, 4>(W + (size_t)b * 262144 + (size_t)ct * 128 * 512, 512,
                           xhT + (size_t)b * 2097152 + (size_t)nt * 128 * 512, 512, 16, sA, sB, acc);

  const int t = threadIdx.x, lane = t & 63, wave = t >> 6;
  const int wm = wave >> 1, wn = wave & 1, m16 = lane & 15, q4 = lane >> 4;
  float g = gm[0];
#pragma unroll
  for (int i = 0; i < 4; ++i)
#pragma unroll
    for (int j = 0; j < 4; ++j)
#pragma unroll
      for (int r2 = 0; r2 < 4; ++r2) {
        int c = ct * 128 + wm * 64 + i * 16 + q4 * 4 + r2;
        int n = nt * 128 + wn * 64 + j * 16 + m16;
        size_t idx = (size_t)b * 2097152 + (size_t)c * 4096 + n;
        out[idx] = g * (acc[i][j][r2] + beta[b * 512 + c]) + h2f(xh[idx]);
      }
}

extern "C" void kernel_launch(void* const* d_in, const int* in_sizes, int n_in,
                              void* d_out, int out_size, void* d_ws, size_t ws_size,
                              hipStream_t stream) {
  const float* x  = (const float*)d_in[0];
  const float* pq = (const float*)d_in[1];
  const float* kw = (const float*)d_in[2];
  const float* kb = (const float*)d_in[3];
  const float* vw = (const float*)d_in[4];
  const float* vb = (const float*)d_in[5];
  const float* gm = (const float*)d_in[6];
  float* out = (float*)d_out;

  // workspace: 94 MB
  char* ws = (char*)d_ws;
  u16*   xh   = (u16*)(ws);                            // [0,32M)  fp16 x [b][o][n]
  u16*   qh   = (u16*)(ws + (32ull << 20));            // [32,36M) dead after sgemm
  float* E    = (float*)(ws + (32ull << 20));          // [32,40M) fp32, live egemm->softmax
  u16*   W    = (u16*)(ws + (36ull << 20));            // [36,40M) live wgemm->outgemm (E dead by then)
  float* Sp0  = (float*)(ws + (40ull << 20));          // [40,48M) split-K partial 0
  u16*   attT = (u16*)(ws + (48ull << 20));            // [48,52M)
  u16*   kwh  = (u16*)(ws + (52ull << 20));            // 512K
  u16*   vwT  = (u16*)(ws + (52ull << 20) + 524288);   // 512K
  char*  sm   = ws + (53ull << 20);                    // small region
  float* qs   = (float*)(sm);
  float* beta = (float*)(sm + 4096);                   // 16K
  u16*   xhT  = (u16*)(ws + (54ull << 20));            // [54,86M) fp16 x^T [b][n][o]
  float* Sp1  = (float*)(ws + (86ull << 20));          // [86,94M) split-K partial 1

  prep_all_kernel<<<dim3(1409), 256, 0, stream>>>(x, xh, xhT, pq, qh, qs, vw, vwT, kw, kwh, beta);
  sgemm_kernel<<<dim3(32, 4, 2), 256, 0, stream>>>(qh, xh, Sp0, Sp1);
  egemm_kernel<<<dim3(64, 8), 256, 0, stream>>>(kwh, Sp0, Sp1, E);
  softmax_kernel<<<dim3(32, 8), 256, 0, stream>>>(E, qs, kb, vb, attT, beta);
  wgemm_kernel<<<dim3(64, 8), 256, 0, stream>>>(attT, vwT, W);
  outgemm_kernel<<<dim3(32, 4, 8), 256, 0, stream>>>(W, xhT, xh, beta, gm, out);
}

// Round 10
// 231.006 us; speedup vs baseline: 1.0789x; 1.0388x over previous
//
#include <hip/hip_runtime.h>

typedef unsigned short u16;
typedef unsigned int u32;
typedef unsigned long long u64;
typedef _Float16 f16x8 __attribute__((ext_vector_type(8)));
typedef float f32x4 __attribute__((ext_vector_type(4)));

__device__ __forceinline__ u16 f2h(float f) {
  union { _Float16 h; u16 u; } c; c.h = (_Float16)f; return c.u;
}
__device__ __forceinline__ float h2f(u16 v) {
  union { u16 u; _Float16 h; } c; c.u = v; return (float)c.h;
}

__device__ __forceinline__ f32x4 mfma16(f16x8 a, f16x8 b, f32x4 c) {
  return __builtin_amdgcn_mfma_f32_16x16x32_f16(a, b, c, 0, 0, 0);
}

// 8 contiguous fp32 -> 8 fp16 (u16)
__device__ __forceinline__ void ld8f(const float* s, u16* o) {
  float4 a = *(const float4*)s;
  float4 b = *(const float4*)(s + 4);
  o[0] = f2h(a.x); o[1] = f2h(a.y); o[2] = f2h(a.z); o[3] = f2h(a.w);
  o[4] = f2h(b.x); o[5] = f2h(b.y); o[6] = f2h(b.z); o[7] = f2h(b.w);
}

// pack two float4-pairs (8 floats) to 8 fp16
__device__ __forceinline__ void cvt8(float4 a, float4 b, u16* o) {
  o[0] = f2h(a.x); o[1] = f2h(a.y); o[2] = f2h(a.z); o[3] = f2h(a.w);
  o[4] = f2h(b.x); o[5] = f2h(b.y); o[6] = f2h(b.z); o[7] = f2h(b.w);
}

// (a0,a1) + (c0,c1) elementwise -> 8 fp16
__device__ __forceinline__ void addcvt8(float4 a0, float4 a1, float4 c0, float4 c1, u16* o) {
  o[0] = f2h(a0.x + c0.x); o[1] = f2h(a0.y + c0.y); o[2] = f2h(a0.z + c0.z); o[3] = f2h(a0.w + c0.w);
  o[4] = f2h(a1.x + c1.x); o[5] = f2h(a1.y + c1.y); o[6] = f2h(a1.z + c1.z); o[7] = f2h(a1.w + c1.w);
}

// async global->LDS 16B direct load. LDS dest wave-uniform base; HW adds lane*16.
__device__ __forceinline__ void glds16(const u16* g, u16* l) {
  __builtin_amdgcn_global_load_lds(
      reinterpret_cast<const __attribute__((address_space(1))) u32*>(reinterpret_cast<u64>(g)),
      reinterpret_cast<__attribute__((address_space(3))) u32*>(reinterpret_cast<u64>(l)),
      16, 0, 0);
}

// ---------------------------------------------------------------------------
// Counted-vmcnt pipelined NT tile core (unchanged).
// ---------------------------------------------------------------------------
template<int TM, int TN, int WM, int WN, int DEPTH>
__device__ __forceinline__ void gemm_core(const u16* __restrict__ A, int lda,
                                          const u16* __restrict__ B, int ldb,
                                          int ksteps, u16* sA, u16* sB, f32x4 acc[TM][TN]) {
  constexpr int NT = WM * WN * 64;
  constexpr int BM = WM * TM * 16, BN = WN * TN * 16;
  constexpr int TILEA = BM * 32, TILEB = BN * 32;   // u16 per buffer
  constexpr int APF = (BM * 4) / NT, BPF = (BN * 4) / NT;  // glds/thread
  constexpr int VPI = APF + BPF;                    // vmem issued per iter
  constexpr int PF = DEPTH - 2;                     // prefetch depth
  static_assert(PF == 1 || PF == 2, "");
  static_assert(APF >= 1 && BPF >= 1, "");

  const int t = threadIdx.x;
  const int lane = t & 63, wave = t >> 6;
  const int wm = wave / WN, wn = wave % WN;
  const int m16 = lane & 15, q4 = lane >> 4;

  int aoff[APF], asl[APF];
#pragma unroll
  for (int p = 0; p < APF; ++p) {
    int s = p * NT + t, row = s >> 2;
    int kc = (s & 3) ^ ((row >> 1) & 3);
    aoff[p] = row * lda + kc * 8;
    asl[p] = (p * NT + (wave << 6)) * 8;  // wave-uniform LDS u16 base
  }
  int boff[BPF], bsl[BPF];
#pragma unroll
  for (int p = 0; p < BPF; ++p) {
    int s = p * NT + t, row = s >> 2;
    int kc = (s & 3) ^ ((row >> 1) & 3);
    boff[p] = row * ldb + kc * 8;
    bsl[p] = (p * NT + (wave << 6)) * 8;
  }

  int aro[TM], bro[TN];
#pragma unroll
  for (int i = 0; i < TM; ++i) {
    int row = wm * TM * 16 + i * 16 + m16;
    aro[i] = row * 32 + ((q4 ^ ((row >> 1) & 3)) << 3);
  }
#pragma unroll
  for (int j = 0; j < TN; ++j) {
    int row = wn * TN * 16 + j * 16 + m16;
    bro[j] = row * 32 + ((q4 ^ ((row >> 1) & 3)) << 3);
  }

  // prologue: stage tiles 0..PF-1 into buffers 0..PF-1
#pragma unroll
  for (int j = 0; j < PF; ++j) {
    const u16* Aj = A + j * 32;
    u16* aS = sA + j * TILEA;
#pragma unroll
    for (int p = 0; p < APF; ++p) glds16(Aj + aoff[p], aS + asl[p]);
    const u16* Bj = B + j * 32;
    u16* bS = sB + j * TILEB;
#pragma unroll
    for (int p = 0; p < BPF; ++p) glds16(Bj + boff[p], bS + bsl[p]);
  }

  int cur = 0, stg = PF;
#pragma unroll 1
  for (int kt = 0; kt < ksteps; ++kt) {
    if (kt + PF < ksteps) {
      const u16* An = A + (size_t)(kt + PF) * 32;
      u16* aS = sA + stg * TILEA;
#pragma unroll
      for (int p = 0; p < APF; ++p) glds16(An + aoff[p], aS + asl[p]);
      const u16* Bn = B + (size_t)(kt + PF) * 32;
      u16* bS = sB + stg * TILEB;
#pragma unroll
      for (int p = 0; p < BPF; ++p) glds16(Bn + boff[p], bS + bsl[p]);
    }
    if (PF == 2 && kt + 2 < ksteps)
      asm volatile("s_waitcnt vmcnt(%0)" :: "n"(2 * VPI) : "memory");
    else if (kt + 1 < ksteps)
      asm volatile("s_waitcnt vmcnt(%0)" :: "n"(VPI) : "memory");
    else
      asm volatile("s_waitcnt vmcnt(0)" ::: "memory");
    __builtin_amdgcn_s_barrier();
    __builtin_amdgcn_sched_barrier(0);

    const u16* aR = sA + cur * TILEA;
    const u16* bR = sB + cur * TILEB;
    f16x8 af[TM], bv[TN];
#pragma unroll
    for (int i = 0; i < TM; ++i) af[i] = *(const f16x8*)&aR[aro[i]];
#pragma unroll
    for (int j = 0; j < TN; ++j) bv[j] = *(const f16x8*)&bR[bro[j]];
#pragma unroll
    for (int i = 0; i < TM; ++i)
#pragma unroll
      for (int j = 0; j < TN; ++j)
        acc[i][j] = mfma16(af[i], bv[j], acc[i][j]);

    cur = (cur + 1 == DEPTH) ? 0 : cur + 1;
    stg = (stg + 1 == DEPTH) ? 0 : stg + 1;
  }
}

// ---------------------------------------------------------------------------
// Merged prep.
// x-role blocks [0,512): full 64x512 slab in LDS (stride-261 u32: phase-1
//   write banks 5(c+e)+s = 2-way free; phase-2 read banks 5n+4sub+j = 2-way
//   free), then xhT written with FULL 64-B LINES PER INSTRUCTION: thread =
//   (row n=t>>2, quarter sub=t&3); each wave instr covers 16 rows x 4
//   contiguous 16B quarters = 16 complete lines -> no cross-instr write
//   combining needed (tests r9's WRITE_SIZE-inflation mechanism).
// [512,1024): q rows; [1024,1280): vwT; [1280,1408): kwh; 1408: beta=0.
// ---------------------------------------------------------------------------
__global__ __launch_bounds__(256) void prep_all_kernel(const float* __restrict__ x,
                                                       u16* __restrict__ xh, u16* __restrict__ xhT,
                                                       const float* __restrict__ q, u16* __restrict__ qh,
                                                       float* __restrict__ qs,
                                                       const float* __restrict__ vw, u16* __restrict__ vwT,
                                                       const float* __restrict__ kw, u16* __restrict__ kwh,
                                                       float* __restrict__ beta) {
  __shared__ __align__(16) u32 TS[64 * 261];  // 66816 B
  int blk = blockIdx.x, t = threadIdx.x;
  if (blk < 512) {
    int nt = blk & 63, b = blk >> 6;
    int s = t & 31;        // o-pair index (o_local = 2s, 2s+1)
    int c = (t >> 5) * 8;  // n_local base
    const float* xbase = x + ((size_t)b * 512 + 2 * s) * 4096 + nt * 64 + c;

    float4 ca0 = *(const float4*)xbase;
    float4 ca1 = *(const float4*)(xbase + 4);
    float4 cb0 = *(const float4*)(xbase + 4096);
    float4 cb1 = *(const float4*)(xbase + 4100);

#pragma unroll 1
    for (int ot = 0; ot < 8; ++ot) {
      float4 na0, na1, nb0, nb1;
      if (ot < 7) {
        const float* np = xbase + (size_t)(ot + 1) * 64 * 4096;
        na0 = *(const float4*)np;
        na1 = *(const float4*)(np + 4);
        nb0 = *(const float4*)(np + 4096);
        nb1 = *(const float4*)(np + 4100);
      }
      u16 r0[8], r1[8];
      cvt8(ca0, ca1, r0);
      cvt8(cb0, cb1, r1);

      // xh pass-through (coalesced)
      u16* xq = xh + ((size_t)b * 512 + ot * 64 + 2 * s) * 4096 + nt * 64 + c;
      *(int4*)xq = *(int4*)r0;
      *(int4*)(xq + 4096) = *(int4*)r1;

      // accumulate transposed slab: TS[n_local][opair], no per-iter barrier
#pragma unroll
      for (int e = 0; e < 8; ++e)
        TS[(c + e) * 261 + ot * 32 + s] = (u32)r0[e] | ((u32)r1[e] << 16);

      ca0 = na0; ca1 = na1; cb0 = nb0; cb1 = nb1;
    }
    __syncthreads();

    // phase 2: full-line-per-instruction write-out.
    // thread: row n = t>>2, quarter sub = t&3. Instr i writes 16 B at byte
    // col i*64 + sub*16 -> per wave: 16 full 64-B lines per instruction.
    int n = t >> 2, sub = t & 3;
    const u32* Trow = TS + n * 261;
    u16* xo = xhT + ((size_t)b * 4096 + nt * 64 + n) * 512;
#pragma unroll
    for (int i = 0; i < 16; ++i) {
      int col = i * 16 + sub * 4;  // u32 index within the 256-u32 row
      u32 vv[4];
      vv[0] = Trow[col]; vv[1] = Trow[col + 1];
      vv[2] = Trow[col + 2]; vv[3] = Trow[col + 3];
      *(int4*)(xo + i * 32 + sub * 8) = *(int4*)vv;
    }
  } else if (blk < 1024) {
    int row = blk - 512;
    float s = 0.f;
#pragma unroll
    for (int p = 0; p < 2; ++p) {
      size_t i = (size_t)row * 4096 + p * 2048 + t * 8;
      u16 o[8];
      ld8f(q + i, o);
#pragma unroll
      for (int e = 0; e < 8; ++e) s += h2f(o[e]);
      *(int4*)&qh[i] = *(int4*)o;
    }
    for (int off = 32; off; off >>= 1) s += __shfl_xor(s, off);
    __shared__ float wsum[4];
    if ((t & 63) == 0) wsum[t >> 6] = s;
    __syncthreads();
    if (t == 0) qs[row] = wsum[0] + wsum[1] + wsum[2] + wsum[3];
  } else if (blk < 1280) {
    int bi = blk - 1024;
    u16* sT = (u16*)TS;  // reuse (needs 32*33 u16)
    int bx = bi & 15, by = bi >> 4;
#pragma unroll
    for (int p = 0; p < 4; ++p) {
      int idx = p * 256 + t; int r = idx >> 5, c = idx & 31;
      sT[r * 33 + c] = f2h(vw[(size_t)(by * 32 + r) * 512 + bx * 32 + c]);
    }
    __syncthreads();
#pragma unroll
    for (int p = 0; p < 4; ++p) {
      int idx = p * 256 + t; int r = idx >> 5, c = idx & 31;
      vwT[(size_t)(bx * 32 + r) * 512 + by * 32 + c] = sT[c * 33 + r];
    }
  } else if (blk < 1408) {
    size_t i = ((size_t)(blk - 1280) * 256 + t) * 8;
    u16 o[8];
    ld8f(kw + i, o);
    *(int4*)&kwh[i] = *(int4*)o;
  } else {
    for (int i = t; i < 4096; i += 256) beta[i] = 0.f;
  }
}

// sgemm split-K: 128x128 tiles, split-2 over K -> 256 blocks.
__global__ __launch_bounds__(256) void sgemm_kernel(const u16* __restrict__ qh, const u16* __restrict__ xh,
                                                    float* __restrict__ Sp0, float* __restrict__ Sp1) {
  __shared__ __align__(16) u16 sA[4 * 128 * 32], sB[4 * 128 * 32];
  int rt = blockIdx.x, jt = blockIdx.y, ks = blockIdx.z;
  int b = rt >> 2, o0 = (rt & 3) * 128;
  f32x4 acc[4][4];
#pragma unroll
  for (int i = 0; i < 4; ++i)
#pragma unroll
    for (int j = 0; j < 4; ++j) acc[i][j] = (f32x4){0.f, 0.f, 0.f, 0.f};
  gemm_core<4, 4, 2, 2, 4>(qh + (size_t)jt * 128 * 4096 + (size_t)ks * 2048, 4096,
                           xh + ((size_t)b * 512 + o0) * 4096 + (size_t)ks * 2048, 4096,
                           64, sA, sB, acc);

  const int t = threadIdx.x, lane = t & 63, wave = t >> 6;
  const int wm = wave >> 1, wn = wave & 1, m16 = lane & 15, q4 = lane >> 4;
  float* Sp = ks ? Sp1 : Sp0;
  float* Ob = Sp + (size_t)b * 262144;
#pragma unroll
  for (int i = 0; i < 4; ++i)
#pragma unroll
    for (int j = 0; j < 4; ++j)
#pragma unroll
      for (int r2 = 0; r2 < 4; ++r2) {
        int y = jt * 128 + wm * 64 + i * 16 + q4 * 4 + r2;
        int o = o0 + wn * 64 + j * 16 + m16;
        Ob[(size_t)y * 512 + o] = acc[i][j][r2];
      }
}

// Fused egemm + split-K reduce.
__global__ __launch_bounds__(256) void egemm_kernel(const u16* __restrict__ kwh,
                                                    const float* __restrict__ Sp0,
                                                    const float* __restrict__ Sp1,
                                                    float* __restrict__ E) {
  __shared__ __align__(16) u16 sA[16 * 2048];  // resident A, 64 KB
  __shared__ __align__(16) u16 sB[3 * 2048];   // B stream, 12 KB
  int xt = blockIdx.x >> 3, yt = blockIdx.x & 7, b = blockIdx.y;
  const int t = threadIdx.x, lane = t & 63, wave = t >> 6;
  const int wm = wave >> 1, wn = wave & 1, m16 = lane & 15, q4 = lane >> 4;

  {
    int row = t >> 2;
    int kc = (t & 3) ^ ((row >> 1) & 3);
    const u16* Abase = kwh + (size_t)(xt * 64 + row) * 512 + kc * 8;
    u16* adst = sA + (t & 192) * 8;
#pragma unroll
    for (int k2 = 0; k2 < 16; ++k2)
      glds16(Abase + k2 * 32, adst + k2 * 2048);
  }

  int srow = t >> 2;
  int skc = (t & 3) ^ ((srow >> 1) & 3);
  const float* b0 = Sp0 + (size_t)b * 262144 + (size_t)(yt * 64 + srow) * 512 + skc * 8;
  const float* b1 = Sp1 + (size_t)b * 262144 + (size_t)(yt * 64 + srow) * 512 + skc * 8;

  float4 pa0, pa1, pa2, pa3, pb0, pb1, pb2, pb3;
  pa0 = *(const float4*)(b0);      pa1 = *(const float4*)(b0 + 4);
  pa2 = *(const float4*)(b1);      pa3 = *(const float4*)(b1 + 4);
  pb0 = *(const float4*)(b0 + 32); pb1 = *(const float4*)(b0 + 36);
  pb2 = *(const float4*)(b1 + 32); pb3 = *(const float4*)(b1 + 36);
  {
    u16 h[8];
    addcvt8(pa0, pa1, pa2, pa3, h);            // tile 0
    *(int4*)&sB[t * 8] = *(int4*)h;
  }
  asm volatile("s_waitcnt vmcnt(0) lgkmcnt(0)" ::: "memory");
  __builtin_amdgcn_s_barrier();

  int aro[2], bro[2];
#pragma unroll
  for (int i = 0; i < 2; ++i) {
    int row = wm * 32 + i * 16 + m16;
    aro[i] = row * 32 + ((q4 ^ ((row >> 1) & 3)) << 3);
  }
#pragma unroll
  for (int j = 0; j < 2; ++j) {
    int row = wn * 32 + j * 16 + m16;
    bro[j] = row * 32 + ((q4 ^ ((row >> 1) & 3)) << 3);
  }

  f32x4 acc[2][2];
#pragma unroll
  for (int i = 0; i < 2; ++i)
#pragma unroll
    for (int j = 0; j < 2; ++j) acc[i][j] = (f32x4){0.f, 0.f, 0.f, 0.f};

#pragma unroll 2
  for (int kt = 0; kt < 16; ++kt) {
    if (kt + 2 < 16) {
      const float* s0 = b0 + (kt + 2) * 32;
      const float* s1 = b1 + (kt + 2) * 32;
      if (kt & 1) {
        pb0 = *(const float4*)s0; pb1 = *(const float4*)(s0 + 4);
        pb2 = *(const float4*)s1; pb3 = *(const float4*)(s1 + 4);
      } else {
        pa0 = *(const float4*)s0; pa1 = *(const float4*)(s0 + 4);
        pa2 = *(const float4*)s1; pa3 = *(const float4*)(s1 + 4);
      }
    }
    if (kt + 1 < 16) {
      u16 h[8];
      if (kt & 1) addcvt8(pa0, pa1, pa2, pa3, h);
      else        addcvt8(pb0, pb1, pb2, pb3, h);
      *(int4*)&sB[((kt + 1) % 3) * 2048 + t * 8] = *(int4*)h;
    }
    asm volatile("s_waitcnt lgkmcnt(0)" ::: "memory");
    __builtin_amdgcn_s_barrier();
    __builtin_amdgcn_sched_barrier(0);

    const u16* aT = sA + kt * 2048;
    const u16* bT = sB + (kt % 3) * 2048;
    f16x8 af[2], bv[2];
#pragma unroll
    for (int i = 0; i < 2; ++i) af[i] = *(const f16x8*)&aT[aro[i]];
#pragma unroll
    for (int j = 0; j < 2; ++j) bv[j] = *(const f16x8*)&bT[bro[j]];
#pragma unroll
    for (int i = 0; i < 2; ++i)
#pragma unroll
      for (int j = 0; j < 2; ++j)
        acc[i][j] = mfma16(af[i], bv[j], acc[i][j]);
  }

  float* O = E + ((size_t)b * 512 + xt * 64) * 512 + yt * 64;
#pragma unroll
  for (int i = 0; i < 2; ++i)
#pragma unroll
    for (int j = 0; j < 2; ++j)
#pragma unroll
      for (int r2 = 0; r2 < 4; ++r2) {
        int row = wm * 32 + i * 16 + q4 * 4 + r2;
        int col = wn * 32 + j * 16 + m16;
        O[(size_t)row * 512 + col] = acc[i][j][r2];
      }
}

// softmax over y of (E[b,x,y]+kb[x]*qs[y]); writes attT fp16; beta += sum_x att*vb[x]
__global__ __launch_bounds__(256) void softmax_kernel(const float* __restrict__ E, const float* __restrict__ qs,
                                                      const float* __restrict__ kb, const float* __restrict__ vb,
                                                      u16* __restrict__ attT, float* __restrict__ beta) {
  __shared__ float sE[16 * 516];
  __shared__ float sM[16], sS[16];
  int i0 = blockIdx.x * 16, b = blockIdx.y, t = threadIdx.x;
  const float* Eb = E + ((size_t)b * 512 + i0) * 512;
  for (int ch = 0; ch < 32; ++ch) {
    int idx = ch * 256 + t;
    int row = idx >> 9, col = idx & 511;
    sE[row * 516 + col] = Eb[(size_t)row * 512 + col] + kb[i0 + row] * qs[col];
  }
  __syncthreads();
  {
    int row = t >> 4, sub = t & 15;
    float mx = -1e30f;
    for (int ii = 0; ii < 32; ++ii) mx = fmaxf(mx, sE[row * 516 + sub + ii * 16]);
    for (int off = 8; off; off >>= 1) mx = fmaxf(mx, __shfl_xor(mx, off));
    float sm = 0.f;
    for (int ii = 0; ii < 32; ++ii) sm += __expf(sE[row * 516 + sub + ii * 16] - mx);
    for (int off = 8; off; off >>= 1) sm += __shfl_xor(sm, off);
    if (sub == 0) { sM[row] = mx; sS[row] = 1.f / sm; }
  }
  __syncthreads();
  float vbr = vb[i0 + (t & 15)];
  u16* Ob = attT + (size_t)b * 262144;
  for (int ch = 0; ch < 32; ++ch) {
    int idx = ch * 256 + t;
    int r = idx & 15, j = idx >> 4;
    float a = __expf(sE[r * 516 + j] - sM[r]) * sS[r];
    Ob[(size_t)j * 512 + i0 + r] = f2h(a);
    float part = a * vbr;
    for (int off = 8; off; off >>= 1) part += __shfl_xor(part, off);
    if (r == 0) atomicAdd(&beta[b * 512 + j], part);
  }
}

// W[b][c][o] = sum_x attT[b][c][x] * vwT[o][x]
__global__ __launch_bounds__(256) void wgemm_kernel(const u16* __restrict__ attT, const u16* __restrict__ vwT,
                                                    u16* __restrict__ W) {
  __shared__ __align__(16) u16 sA[4 * 64 * 32], sB[4 * 64 * 32];
  int ct = blockIdx.x >> 3, ot = blockIdx.x & 7, b = blockIdx.y;
  f32x4 acc[2][2];
#pragma unroll
  for (int i = 0; i < 2; ++i)
#pragma unroll
    for (int j = 0; j < 2; ++j) acc[i][j] = (f32x4){0.f, 0.f, 0.f, 0.f};
  gemm_core<2, 2, 2, 2, 4>(attT + (size_t)b * 262144 + (size_t)ct * 64 * 512, 512,
                           vwT + (size_t)ot * 64 * 512, 512, 16, sA, sB, acc);

  const int t = threadIdx.x, lane = t & 63, wave = t >> 6;
  const int wm = wave >> 1, wn = wave & 1, m16 = lane & 15, q4 = lane >> 4;
  u16* O = W + (size_t)b * 262144 + (size_t)(ct * 64) * 512 + ot * 64;
#pragma unroll
  for (int i = 0; i < 2; ++i)
#pragma unroll
    for (int j = 0; j < 2; ++j)
#pragma unroll
      for (int r2 = 0; r2 < 4; ++r2) {
        int row = wm * 32 + i * 16 + q4 * 4 + r2;
        int col = wn * 32 + j * 16 + m16;
        O[(size_t)row * 512 + col] = f2h(acc[i][j][r2]);
      }
}

// out = gamma*(W·xhT + beta) + xh
__global__ __launch_bounds__(256) void outgemm_kernel(const u16* __restrict__ W, const u16* __restrict__ xhT,
                                                      const u16* __restrict__ xh, const float* __restrict__ beta,
                                                      const float* __restrict__ gm, float* __restrict__ out) {
  __shared__ __align__(16) u16 sA[4 * 128 * 32], sB[4 * 128 * 32];
  int nt = blockIdx.x, ct = blockIdx.y, b = blockIdx.z;
  f32x4 acc[4][4];
#pragma unroll
  for (int i = 0; i < 4; ++i)
#pragma unroll
    for (int j = 0; j < 4; ++j) acc[i][j] = (f32x4){0.f, 0.f, 0.f, 0.f};
  gemm_core<4, 4, 2, 2, 4>(W + (size_t)b * 262144 + (size_t)ct * 128 * 512, 512,
                           xhT + (size_t)b * 2097152 + (size_t)nt * 128 * 512, 512, 16, sA, sB, acc);

  const int t = threadIdx.x, lane = t & 63, wave = t >> 6;
  const int wm = wave >> 1, wn = wave & 1, m16 = lane & 15, q4 = lane >> 4;
  float g = gm[0];
#pragma unroll
  for (int i = 0; i < 4; ++i)
#pragma unroll
    for (int j = 0; j < 4; ++j)
#pragma unroll
      for (int r2 = 0; r2 < 4; ++r2) {
        int c = ct * 128 + wm * 64 + i * 16 + q4 * 4 + r2;
        int n = nt * 128 + wn * 64 + j * 16 + m16;
        size_t idx = (size_t)b * 2097152 + (size_t)c * 4096 + n;
        out[idx] = g * (acc[i][j][r2] + beta[b * 512 + c]) + h2f(xh[idx]);
      }
}

extern "C" void kernel_launch(void* const* d_in, const int* in_sizes, int n_in,
                              void* d_out, int out_size, void* d_ws, size_t ws_size,
                              hipStream_t stream) {
  const float* x  = (const float*)d_in[0];
  const float* pq = (const float*)d_in[1];
  const float* kw = (const float*)d_in[2];
  const float* kb = (const float*)d_in[3];
  const float* vw = (const float*)d_in[4];
  const float* vb = (const float*)d_in[5];
  const float* gm = (const float*)d_in[6];
  float* out = (float*)d_out;

  // workspace: 94 MB
  char* ws = (char*)d_ws;
  u16*   xh   = (u16*)(ws);                            // [0,32M)  fp16 x [b][o][n]
  u16*   qh   = (u16*)(ws + (32ull << 20));            // [32,36M) dead after sgemm
  float* E    = (float*)(ws + (32ull << 20));          // [32,40M) fp32, live egemm->softmax
  u16*   W    = (u16*)(ws + (36ull << 20));            // [36,40M) live wgemm->outgemm (E dead by then)
  float* Sp0  = (float*)(ws + (40ull << 20));          // [40,48M) split-K partial 0
  u16*   attT = (u16*)(ws + (48ull << 20));            // [48,52M)
  u16*   kwh  = (u16*)(ws + (52ull << 20));            // 512K
  u16*   vwT  = (u16*)(ws + (52ull << 20) + 524288);   // 512K
  char*  sm   = ws + (53ull << 20);                    // small region
  float* qs   = (float*)(sm);
  float* beta = (float*)(sm + 4096);                   // 16K
  u16*   xhT  = (u16*)(ws + (54ull << 20));            // [54,86M) fp16 x^T [b][n][o]
  float* Sp1  = (float*)(ws + (86ull << 20));          // [86,94M) split-K partial 1

  prep_all_kernel<<<dim3(1409), 256, 0, stream>>>(x, xh, xhT, pq, qh, qs, vw, vwT, kw, kwh, beta);
  sgemm_kernel<<<dim3(32, 4, 2), 256, 0, stream>>>(qh, xh, Sp0, Sp1);
  egemm_kernel<<<dim3(64, 8), 256, 0, stream>>>(kwh, Sp0, Sp1, E);
  softmax_kernel<<<dim3(32, 8), 256, 0, stream>>>(E, qs, kb, vb, attT, beta);
  wgemm_kernel<<<dim3(64, 8), 256, 0, stream>>>(attT, vwT, W);
  outgemm_kernel<<<dim3(32, 4, 8), 256, 0, stream>>>(W, xhT, xh, beta, gm, out);
}

// Round 11
// 220.692 us; speedup vs baseline: 1.1294x; 1.0467x over previous
//
#include <hip/hip_runtime.h>

typedef unsigned short u16;
typedef unsigned int u32;
typedef unsigned long long u64;
typedef _Float16 f16x8 __attribute__((ext_vector_type(8)));
typedef float f32x4 __attribute__((ext_vector_type(4)));

__device__ __forceinline__ u16 f2h(float f) {
  union { _Float16 h; u16 u; } c; c.h = (_Float16)f; return c.u;
}
__device__ __forceinline__ float h2f(u16 v) {
  union { u16 u; _Float16 h; } c; c.u = v; return (float)c.h;
}

__device__ __forceinline__ f32x4 mfma16(f16x8 a, f16x8 b, f32x4 c) {
  return __builtin_amdgcn_mfma_f32_16x16x32_f16(a, b, c, 0, 0, 0);
}

// 8 contiguous fp32 -> 8 fp16 (u16)
__device__ __forceinline__ void ld8f(const float* s, u16* o) {
  float4 a = *(const float4*)s;
  float4 b = *(const float4*)(s + 4);
  o[0] = f2h(a.x); o[1] = f2h(a.y); o[2] = f2h(a.z); o[3] = f2h(a.w);
  o[4] = f2h(b.x); o[5] = f2h(b.y); o[6] = f2h(b.z); o[7] = f2h(b.w);
}

// (a0,a1) + (c0,c1) elementwise -> 8 fp16
__device__ __forceinline__ void addcvt8(float4 a0, float4 a1, float4 c0, float4 c1, u16* o) {
  o[0] = f2h(a0.x + c0.x); o[1] = f2h(a0.y + c0.y); o[2] = f2h(a0.z + c0.z); o[3] = f2h(a0.w + c0.w);
  o[4] = f2h(a1.x + c1.x); o[5] = f2h(a1.y + c1.y); o[6] = f2h(a1.z + c1.z); o[7] = f2h(a1.w + c1.w);
}

// async global->LDS 16B direct load. LDS dest wave-uniform base; HW adds lane*16.
__device__ __forceinline__ void glds16(const u16* g, u16* l) {
  __builtin_amdgcn_global_load_lds(
      reinterpret_cast<const __attribute__((address_space(1))) u32*>(reinterpret_cast<u64>(g)),
      reinterpret_cast<__attribute__((address_space(3))) u32*>(reinterpret_cast<u64>(l)),
      16, 0, 0);
}

// ---------------------------------------------------------------------------
// Counted-vmcnt pipelined NT tile core (unchanged; used by sgemm/wgemm).
// ---------------------------------------------------------------------------
template<int TM, int TN, int WM, int WN, int DEPTH>
__device__ __forceinline__ void gemm_core(const u16* __restrict__ A, int lda,
                                          const u16* __restrict__ B, int ldb,
                                          int ksteps, u16* sA, u16* sB, f32x4 acc[TM][TN]) {
  constexpr int NT = WM * WN * 64;
  constexpr int BM = WM * TM * 16, BN = WN * TN * 16;
  constexpr int TILEA = BM * 32, TILEB = BN * 32;   // u16 per buffer
  constexpr int APF = (BM * 4) / NT, BPF = (BN * 4) / NT;  // glds/thread
  constexpr int VPI = APF + BPF;                    // vmem issued per iter
  constexpr int PF = DEPTH - 2;                     // prefetch depth
  static_assert(PF == 1 || PF == 2, "");
  static_assert(APF >= 1 && BPF >= 1, "");

  const int t = threadIdx.x;
  const int lane = t & 63, wave = t >> 6;
  const int wm = wave / WN, wn = wave % WN;
  const int m16 = lane & 15, q4 = lane >> 4;

  int aoff[APF], asl[APF];
#pragma unroll
  for (int p = 0; p < APF; ++p) {
    int s = p * NT + t, row = s >> 2;
    int kc = (s & 3) ^ ((row >> 1) & 3);
    aoff[p] = row * lda + kc * 8;
    asl[p] = (p * NT + (wave << 6)) * 8;  // wave-uniform LDS u16 base
  }
  int boff[BPF], bsl[BPF];
#pragma unroll
  for (int p = 0; p < BPF; ++p) {
    int s = p * NT + t, row = s >> 2;
    int kc = (s & 3) ^ ((row >> 1) & 3);
    boff[p] = row * ldb + kc * 8;
    bsl[p] = (p * NT + (wave << 6)) * 8;
  }

  int aro[TM], bro[TN];
#pragma unroll
  for (int i = 0; i < TM; ++i) {
    int row = wm * TM * 16 + i * 16 + m16;
    aro[i] = row * 32 + ((q4 ^ ((row >> 1) & 3)) << 3);
  }
#pragma unroll
  for (int j = 0; j < TN; ++j) {
    int row = wn * TN * 16 + j * 16 + m16;
    bro[j] = row * 32 + ((q4 ^ ((row >> 1) & 3)) << 3);
  }

  // prologue: stage tiles 0..PF-1 into buffers 0..PF-1
#pragma unroll
  for (int j = 0; j < PF; ++j) {
    const u16* Aj = A + j * 32;
    u16* aS = sA + j * TILEA;
#pragma unroll
    for (int p = 0; p < APF; ++p) glds16(Aj + aoff[p], aS + asl[p]);
    const u16* Bj = B + j * 32;
    u16* bS = sB + j * TILEB;
#pragma unroll
    for (int p = 0; p < BPF; ++p) glds16(Bj + boff[p], bS + bsl[p]);
  }

  int cur = 0, stg = PF;
#pragma unroll 1
  for (int kt = 0; kt < ksteps; ++kt) {
    if (kt + PF < ksteps) {
      const u16* An = A + (size_t)(kt + PF) * 32;
      u16* aS = sA + stg * TILEA;
#pragma unroll
      for (int p = 0; p < APF; ++p) glds16(An + aoff[p], aS + asl[p]);
      const u16* Bn = B + (size_t)(kt + PF) * 32;
      u16* bS = sB + stg * TILEB;
#pragma unroll
      for (int p = 0; p < BPF; ++p) glds16(Bn + boff[p], bS + bsl[p]);
    }
    if (PF == 2 && kt + 2 < ksteps)
      asm volatile("s_waitcnt vmcnt(%0)" :: "n"(2 * VPI) : "memory");
    else if (kt + 1 < ksteps)
      asm volatile("s_waitcnt vmcnt(%0)" :: "n"(VPI) : "memory");
    else
      asm volatile("s_waitcnt vmcnt(0)" ::: "memory");
    __builtin_amdgcn_s_barrier();
    __builtin_amdgcn_sched_barrier(0);

    const u16* aR = sA + cur * TILEA;
    const u16* bR = sB + cur * TILEB;
    f16x8 af[TM], bv[TN];
#pragma unroll
    for (int i = 0; i < TM; ++i) af[i] = *(const f16x8*)&aR[aro[i]];
#pragma unroll
    for (int j = 0; j < TN; ++j) bv[j] = *(const f16x8*)&bR[bro[j]];
#pragma unroll
    for (int i = 0; i < TM; ++i)
#pragma unroll
      for (int j = 0; j < TN; ++j)
        acc[i][j] = mfma16(af[i], bv[j], acc[i][j]);

    cur = (cur + 1 == DEPTH) ? 0 : cur + 1;
    stg = (stg + 1 == DEPTH) ? 0 : stg + 1;
  }
}

// ---------------------------------------------------------------------------
// NNB tile core for outgemm: C[128,128] += A[128,K] * B[K,128].
// A (W): K-contiguous, glds16-staged, triple-buffered, PF=1 (as gemm_core).
// B (xh): [K][n] row-major. Reg-loaded EARLY (b128 x2), transposed
//   ds_write_b32 LATE (post-barrier) into a double-buffered LDS tile.
//   LDS tile [n][32 u16]; phys 16B-chunk c'' = (k>>3) ^ ((n>>1)&3) ^ ((n>>3)&3)
//   on BOTH write offsets and fragment reads. Hand-enumerated banks:
//   writes 4-way max (16 banks x 4 lanes), reads <=2-way. All extracts static.
// Race layout: B writes post-barrier -> D=2 safe; A glds D=3 (r2/r10 proof).
// ---------------------------------------------------------------------------
__device__ __forceinline__ void gemm_nnb(const u16* __restrict__ A, int lda,
                                         const u16* __restrict__ B, int ldb,
                                         int ksteps, u16* sA, u16* sB, f32x4 acc[4][4]) {
  const int t = threadIdx.x;
  const int lane = t & 63, wave = t >> 6;
  const int wm = wave >> 1, wn = wave & 1;
  const int m16 = lane & 15, q4 = lane >> 4;
  constexpr int TILE = 128 * 32;

  int aoff[2], asl[2];
#pragma unroll
  for (int p = 0; p < 2; ++p) {
    int s = p * 256 + t, row = s >> 2;
    int kc = (s & 3) ^ ((row >> 1) & 3);
    aoff[p] = row * lda + kc * 8;
    asl[p] = (p * 256 + (wave << 6)) * 8;
  }
  int aro[4];
#pragma unroll
  for (int i = 0; i < 4; ++i) {
    int row = wm * 64 + i * 16 + m16;
    aro[i] = row * 32 + ((q4 ^ ((row >> 1) & 3)) << 3);
  }

  const int kk = (t >> 4) * 2;  // k-row pair (0..30)
  const int nn = (t & 15) * 8;  // col group
  int bwo[8];
#pragma unroll
  for (int e = 0; e < 8; ++e) {
    int n = nn + e;
    int cc = (kk >> 3) ^ ((n >> 1) & 3) ^ ((n >> 3) & 3);
    bwo[e] = n * 32 + (cc << 3) + (kk & 7);
  }
  int bro[4];
#pragma unroll
  for (int j = 0; j < 4; ++j) {
    int n = wn * 64 + j * 16 + m16;
    int cc = q4 ^ ((n >> 1) & 3) ^ ((n >> 3) & 3);
    bro[j] = n * 32 + (cc << 3);
  }

  u16 *aR = sA, *aS = sA + TILE, *aT = sA + 2 * TILE;
  u16 *bR = sB, *bS = sB + TILE;

  // prologue: tile 0
  int4 nb0, nb1;
  {
    const u16* src = B + (size_t)kk * ldb + nn;
    nb0 = *(const int4*)src;
    nb1 = *(const int4*)(src + ldb);
    __builtin_amdgcn_sched_barrier(0);
  }
  glds16(A + aoff[0], aR + asl[0]);
  glds16(A + aoff[1], aR + asl[1]);
  {
    union { int4 v; u16 h[8]; } u0, u1; u0.v = nb0; u1.v = nb1;
#pragma unroll
    for (int e = 0; e < 8; ++e)
      *(u32*)&bR[bwo[e]] = (u32)u0.h[e] | ((u32)u1.h[e] << 16);
  }

#pragma unroll 1
  for (int kt = 0; kt < ksteps; ++kt) {
    const bool more = kt + 1 < ksteps;
    if (more) {
      const u16* src = B + ((size_t)(kt + 1) * 32 + kk) * ldb + nn;
      nb0 = *(const int4*)src;
      nb1 = *(const int4*)(src + ldb);
      __builtin_amdgcn_sched_barrier(0);  // keep B-loads oldest of this iter
      const u16* An = A + (kt + 1) * 32;
      glds16(An + aoff[0], aS + asl[0]);
      glds16(An + aoff[1], aS + asl[1]);
      // outstanding: A(kt)=2 oldest + B(kt+1)=2 + A(kt+1)=2. Drain A(kt),
      // keep the 4 newest in flight across the barrier. lgkm publishes
      // previous iteration's B ds_writes.
      asm volatile("s_waitcnt vmcnt(4) lgkmcnt(0)" ::: "memory");
    } else {
      asm volatile("s_waitcnt vmcnt(0) lgkmcnt(0)" ::: "memory");
    }
    __builtin_amdgcn_s_barrier();
    __builtin_amdgcn_sched_barrier(0);

    f16x8 af[4], bv[4];
#pragma unroll
    for (int i = 0; i < 4; ++i) af[i] = *(const f16x8*)&aR[aro[i]];
#pragma unroll
    for (int j = 0; j < 4; ++j) bv[j] = *(const f16x8*)&bR[bro[j]];
#pragma unroll
    for (int i = 0; i < 4; ++i)
#pragma unroll
      for (int j = 0; j < 4; ++j)
        acc[i][j] = mfma16(af[i], bv[j], acc[i][j]);

    if (more) {  // transposed write of tile kt+1 (post-barrier: D=2 safe)
      union { int4 v; u16 h[8]; } u0, u1; u0.v = nb0; u1.v = nb1;
#pragma unroll
      for (int e = 0; e < 8; ++e)
        *(u32*)&bS[bwo[e]] = (u32)u0.h[e] | ((u32)u1.h[e] << 16);
    }
    { u16* x2 = aR; aR = aS; aS = aT; aT = x2; }
    { u16* x2 = bR; bR = bS; bS = x2; }
  }
}

// ---------------------------------------------------------------------------
// Merged prep — pure streaming (xhT eliminated; transpose moved to outgemm).
// [0,2048): x -> xh, fully contiguous/coalesced (32 KB read + 16 KB write
//   per block). [2048,2560): q rows; [2560,2816): vwT; [2816,2944): kwh;
//   2944: beta = 0.
// ---------------------------------------------------------------------------
__global__ __launch_bounds__(256) void prep_all_kernel(const float* __restrict__ x,
                                                       u16* __restrict__ xh,
                                                       const float* __restrict__ q, u16* __restrict__ qh,
                                                       float* __restrict__ qs,
                                                       const float* __restrict__ vw, u16* __restrict__ vwT,
                                                       const float* __restrict__ kw, u16* __restrict__ kwh,
                                                       float* __restrict__ beta) {
  __shared__ u16 sT[32 * 33];
  int blk = blockIdx.x, t = threadIdx.x;
  if (blk < 2048) {
    size_t base = (size_t)blk * 8192;
#pragma unroll
    for (int p = 0; p < 4; ++p) {
      size_t i = base + p * 2048 + t * 8;
      u16 o[8];
      ld8f(x + i, o);
      *(int4*)&xh[i] = *(int4*)o;
    }
  } else if (blk < 2560) {
    int row = blk - 2048;
    float s = 0.f;
#pragma unroll
    for (int p = 0; p < 2; ++p) {
      size_t i = (size_t)row * 4096 + p * 2048 + t * 8;
      u16 o[8];
      ld8f(q + i, o);
#pragma unroll
      for (int e = 0; e < 8; ++e) s += h2f(o[e]);
      *(int4*)&qh[i] = *(int4*)o;
    }
    for (int off = 32; off; off >>= 1) s += __shfl_xor(s, off);
    __shared__ float wsum[4];
    if ((t & 63) == 0) wsum[t >> 6] = s;
    __syncthreads();
    if (t == 0) qs[row] = wsum[0] + wsum[1] + wsum[2] + wsum[3];
  } else if (blk < 2816) {
    int bi = blk - 2560;
    int bx = bi & 15, by = bi >> 4;
#pragma unroll
    for (int p = 0; p < 4; ++p) {
      int idx = p * 256 + t; int r = idx >> 5, c = idx & 31;
      sT[r * 33 + c] = f2h(vw[(size_t)(by * 32 + r) * 512 + bx * 32 + c]);
    }
    __syncthreads();
#pragma unroll
    for (int p = 0; p < 4; ++p) {
      int idx = p * 256 + t; int r = idx >> 5, c = idx & 31;
      vwT[(size_t)(bx * 32 + r) * 512 + by * 32 + c] = sT[c * 33 + r];
    }
  } else if (blk < 2944) {
    size_t i = ((size_t)(blk - 2816) * 256 + t) * 8;
    u16 o[8];
    ld8f(kw + i, o);
    *(int4*)&kwh[i] = *(int4*)o;
  } else {
    for (int i = t; i < 4096; i += 256) beta[i] = 0.f;
  }
}

// sgemm split-K: 128x128 tiles, split-2 over K -> 256 blocks.
__global__ __launch_bounds__(256) void sgemm_kernel(const u16* __restrict__ qh, const u16* __restrict__ xh,
                                                    float* __restrict__ Sp0, float* __restrict__ Sp1) {
  __shared__ __align__(16) u16 sA[4 * 128 * 32], sB[4 * 128 * 32];
  int rt = blockIdx.x, jt = blockIdx.y, ks = blockIdx.z;
  int b = rt >> 2, o0 = (rt & 3) * 128;
  f32x4 acc[4][4];
#pragma unroll
  for (int i = 0; i < 4; ++i)
#pragma unroll
    for (int j = 0; j < 4; ++j) acc[i][j] = (f32x4){0.f, 0.f, 0.f, 0.f};
  gemm_core<4, 4, 2, 2, 4>(qh + (size_t)jt * 128 * 4096 + (size_t)ks * 2048, 4096,
                           xh + ((size_t)b * 512 + o0) * 4096 + (size_t)ks * 2048, 4096,
                           64, sA, sB, acc);

  const int t = threadIdx.x, lane = t & 63, wave = t >> 6;
  const int wm = wave >> 1, wn = wave & 1, m16 = lane & 15, q4 = lane >> 4;
  float* Sp = ks ? Sp1 : Sp0;
  float* Ob = Sp + (size_t)b * 262144;
#pragma unroll
  for (int i = 0; i < 4; ++i)
#pragma unroll
    for (int j = 0; j < 4; ++j)
#pragma unroll
      for (int r2 = 0; r2 < 4; ++r2) {
        int y = jt * 128 + wm * 64 + i * 16 + q4 * 4 + r2;
        int o = o0 + wn * 64 + j * 16 + m16;
        Ob[(size_t)y * 512 + o] = acc[i][j][r2];
      }
}

// Fused egemm + split-K reduce.
__global__ __launch_bounds__(256) void egemm_kernel(const u16* __restrict__ kwh,
                                                    const float* __restrict__ Sp0,
                                                    const float* __restrict__ Sp1,
                                                    float* __restrict__ E) {
  __shared__ __align__(16) u16 sA[16 * 2048];  // resident A, 64 KB
  __shared__ __align__(16) u16 sB[3 * 2048];   // B stream, 12 KB
  int xt = blockIdx.x >> 3, yt = blockIdx.x & 7, b = blockIdx.y;
  const int t = threadIdx.x, lane = t & 63, wave = t >> 6;
  const int wm = wave >> 1, wn = wave & 1, m16 = lane & 15, q4 = lane >> 4;

  {
    int row = t >> 2;
    int kc = (t & 3) ^ ((row >> 1) & 3);
    const u16* Abase = kwh + (size_t)(xt * 64 + row) * 512 + kc * 8;
    u16* adst = sA + (t & 192) * 8;
#pragma unroll
    for (int k2 = 0; k2 < 16; ++k2)
      glds16(Abase + k2 * 32, adst + k2 * 2048);
  }

  int srow = t >> 2;
  int skc = (t & 3) ^ ((srow >> 1) & 3);
  const float* b0 = Sp0 + (size_t)b * 262144 + (size_t)(yt * 64 + srow) * 512 + skc * 8;
  const float* b1 = Sp1 + (size_t)b * 262144 + (size_t)(yt * 64 + srow) * 512 + skc * 8;

  float4 pa0, pa1, pa2, pa3, pb0, pb1, pb2, pb3;
  pa0 = *(const float4*)(b0);      pa1 = *(const float4*)(b0 + 4);
  pa2 = *(const float4*)(b1);      pa3 = *(const float4*)(b1 + 4);
  pb0 = *(const float4*)(b0 + 32); pb1 = *(const float4*)(b0 + 36);
  pb2 = *(const float4*)(b1 + 32); pb3 = *(const float4*)(b1 + 36);
  {
    u16 h[8];
    addcvt8(pa0, pa1, pa2, pa3, h);            // tile 0
    *(int4*)&sB[t * 8] = *(int4*)h;
  }
  asm volatile("s_waitcnt vmcnt(0) lgkmcnt(0)" ::: "memory");
  __builtin_amdgcn_s_barrier();

  int aro[2], bro[2];
#pragma unroll
  for (int i = 0; i < 2; ++i) {
    int row = wm * 32 + i * 16 + m16;
    aro[i] = row * 32 + ((q4 ^ ((row >> 1) & 3)) << 3);
  }
#pragma unroll
  for (int j = 0; j < 2; ++j) {
    int row = wn * 32 + j * 16 + m16;
    bro[j] = row * 32 + ((q4 ^ ((row >> 1) & 3)) << 3);
  }

  f32x4 acc[2][2];
#pragma unroll
  for (int i = 0; i < 2; ++i)
#pragma unroll
    for (int j = 0; j < 2; ++j) acc[i][j] = (f32x4){0.f, 0.f, 0.f, 0.f};

#pragma unroll 2
  for (int kt = 0; kt < 16; ++kt) {
    if (kt + 2 < 16) {
      const float* s0 = b0 + (kt + 2) * 32;
      const float* s1 = b1 + (kt + 2) * 32;
      if (kt & 1) {
        pb0 = *(const float4*)s0; pb1 = *(const float4*)(s0 + 4);
        pb2 = *(const float4*)s1; pb3 = *(const float4*)(s1 + 4);
      } else {
        pa0 = *(const float4*)s0; pa1 = *(const float4*)(s0 + 4);
        pa2 = *(const float4*)s1; pa3 = *(const float4*)(s1 + 4);
      }
    }
    if (kt + 1 < 16) {
      u16 h[8];
      if (kt & 1) addcvt8(pa0, pa1, pa2, pa3, h);
      else        addcvt8(pb0, pb1, pb2, pb3, h);
      *(int4*)&sB[((kt + 1) % 3) * 2048 + t * 8] = *(int4*)h;
    }
    asm volatile("s_waitcnt lgkmcnt(0)" ::: "memory");
    __builtin_amdgcn_s_barrier();
    __builtin_amdgcn_sched_barrier(0);

    const u16* aT = sA + kt * 2048;
    const u16* bT = sB + (kt % 3) * 2048;
    f16x8 af[2], bv[2];
#pragma unroll
    for (int i = 0; i < 2; ++i) af[i] = *(const f16x8*)&aT[aro[i]];
#pragma unroll
    for (int j = 0; j < 2; ++j) bv[j] = *(const f16x8*)&bT[bro[j]];
#pragma unroll
    for (int i = 0; i < 2; ++i)
#pragma unroll
      for (int j = 0; j < 2; ++j)
        acc[i][j] = mfma16(af[i], bv[j], acc[i][j]);
  }

  float* O = E + ((size_t)b * 512 + xt * 64) * 512 + yt * 64;
#pragma unroll
  for (int i = 0; i < 2; ++i)
#pragma unroll
    for (int j = 0; j < 2; ++j)
#pragma unroll
      for (int r2 = 0; r2 < 4; ++r2) {
        int row = wm * 32 + i * 16 + q4 * 4 + r2;
        int col = wn * 32 + j * 16 + m16;
        O[(size_t)row * 512 + col] = acc[i][j][r2];
      }
}

// softmax over y of (E[b,x,y]+kb[x]*qs[y]); writes attT fp16; beta += sum_x att*vb[x]
__global__ __launch_bounds__(256) void softmax_kernel(const float* __restrict__ E, const float* __restrict__ qs,
                                                      const float* __restrict__ kb, const float* __restrict__ vb,
                                                      u16* __restrict__ attT, float* __restrict__ beta) {
  __shared__ float sE[16 * 516];
  __shared__ float sM[16], sS[16];
  int i0 = blockIdx.x * 16, b = blockIdx.y, t = threadIdx.x;
  const float* Eb = E + ((size_t)b * 512 + i0) * 512;
  for (int ch = 0; ch < 32; ++ch) {
    int idx = ch * 256 + t;
    int row = idx >> 9, col = idx & 511;
    sE[row * 516 + col] = Eb[(size_t)row * 512 + col] + kb[i0 + row] * qs[col];
  }
  __syncthreads();
  {
    int row = t >> 4, sub = t & 15;
    float mx = -1e30f;
    for (int ii = 0; ii < 32; ++ii) mx = fmaxf(mx, sE[row * 516 + sub + ii * 16]);
    for (int off = 8; off; off >>= 1) mx = fmaxf(mx, __shfl_xor(mx, off));
    float sm = 0.f;
    for (int ii = 0; ii < 32; ++ii) sm += __expf(sE[row * 516 + sub + ii * 16] - mx);
    for (int off = 8; off; off >>= 1) sm += __shfl_xor(sm, off);
    if (sub == 0) { sM[row] = mx; sS[row] = 1.f / sm; }
  }
  __syncthreads();
  float vbr = vb[i0 + (t & 15)];
  u16* Ob = attT + (size_t)b * 262144;
  for (int ch = 0; ch < 32; ++ch) {
    int idx = ch * 256 + t;
    int r = idx & 15, j = idx >> 4;
    float a = __expf(sE[r * 516 + j] - sM[r]) * sS[r];
    Ob[(size_t)j * 512 + i0 + r] = f2h(a);
    float part = a * vbr;
    for (int off = 8; off; off >>= 1) part += __shfl_xor(part, off);
    if (r == 0) atomicAdd(&beta[b * 512 + j], part);
  }
}

// W[b][c][o] = sum_x attT[b][c][x] * vwT[o][x]
__global__ __launch_bounds__(256) void wgemm_kernel(const u16* __restrict__ attT, const u16* __restrict__ vwT,
                                                    u16* __restrict__ W) {
  __shared__ __align__(16) u16 sA[4 * 64 * 32], sB[4 * 64 * 32];
  int ct = blockIdx.x >> 3, ot = blockIdx.x & 7, b = blockIdx.y;
  f32x4 acc[2][2];
#pragma unroll
  for (int i = 0; i < 2; ++i)
#pragma unroll
    for (int j = 0; j < 2; ++j) acc[i][j] = (f32x4){0.f, 0.f, 0.f, 0.f};
  gemm_core<2, 2, 2, 2, 4>(attT + (size_t)b * 262144 + (size_t)ct * 64 * 512, 512,
                           vwT + (size_t)ot * 64 * 512, 512, 16, sA, sB, acc);

  const int t = threadIdx.x, lane = t & 63, wave = t >> 6;
  const int wm = wave >> 1, wn = wave & 1, m16 = lane & 15, q4 = lane >> 4;
  u16* O = W + (size_t)b * 262144 + (size_t)(ct * 64) * 512 + ot * 64;
#pragma unroll
  for (int i = 0; i < 2; ++i)
#pragma unroll
    for (int j = 0; j < 2; ++j)
#pragma unroll
      for (int r2 = 0; r2 < 4; ++r2) {
        int row = wm * 32 + i * 16 + q4 * 4 + r2;
        int col = wn * 32 + j * 16 + m16;
        O[(size_t)row * 512 + col] = f2h(acc[i][j][r2]);
      }
}

// out = gamma*(W·xh + beta) + xh  — NN GEMM via in-kernel transpose staging.
__global__ __launch_bounds__(256) void outgemm_kernel(const u16* __restrict__ W, const u16* __restrict__ xh,
                                                      const float* __restrict__ beta,
                                                      const float* __restrict__ gm, float* __restrict__ out) {
  __shared__ __align__(16) u16 sA[3 * 128 * 32], sB[2 * 128 * 32];  // 40 KB
  int nt = blockIdx.x, ct = blockIdx.y, b = blockIdx.z;
  f32x4 acc[4][4];
#pragma unroll
  for (int i = 0; i < 4; ++i)
#pragma unroll
    for (int j = 0; j < 4; ++j) acc[i][j] = (f32x4){0.f, 0.f, 0.f, 0.f};
  gemm_nnb(W + (size_t)b * 262144 + (size_t)ct * 128 * 512, 512,
           xh + (size_t)b * 2097152 + nt * 128, 4096, 16, sA, sB, acc);

  const int t = threadIdx.x, lane = t & 63, wave = t >> 6;
  const int wm = wave >> 1, wn = wave & 1, m16 = lane & 15, q4 = lane >> 4;
  float g = gm[0];
#pragma unroll
  for (int i = 0; i < 4; ++i)
#pragma unroll
    for (int j = 0; j < 4; ++j)
#pragma unroll
      for (int r2 = 0; r2 < 4; ++r2) {
        int c = ct * 128 + wm * 64 + i * 16 + q4 * 4 + r2;
        int n = nt * 128 + wn * 64 + j * 16 + m16;
        size_t idx = (size_t)b * 2097152 + (size_t)c * 4096 + n;
        out[idx] = g * (acc[i][j][r2] + beta[b * 512 + c]) + h2f(xh[idx]);
      }
}

extern "C" void kernel_launch(void* const* d_in, const int* in_sizes, int n_in,
                              void* d_out, int out_size, void* d_ws, size_t ws_size,
                              hipStream_t stream) {
  const float* x  = (const float*)d_in[0];
  const float* pq = (const float*)d_in[1];
  const float* kw = (const float*)d_in[2];
  const float* kb = (const float*)d_in[3];
  const float* vw = (const float*)d_in[4];
  const float* vb = (const float*)d_in[5];
  const float* gm = (const float*)d_in[6];
  float* out = (float*)d_out;

  // workspace (xhT eliminated; layout otherwise unchanged)
  char* ws = (char*)d_ws;
  u16*   xh   = (u16*)(ws);                            // [0,32M)  fp16 x [b][o][n]
  u16*   qh   = (u16*)(ws + (32ull << 20));            // [32,36M) dead after sgemm
  float* E    = (float*)(ws + (32ull << 20));          // [32,40M) fp32, live egemm->softmax
  u16*   W    = (u16*)(ws + (36ull << 20));            // [36,40M) live wgemm->outgemm
  float* Sp0  = (float*)(ws + (40ull << 20));          // [40,48M) split-K partial 0
  u16*   attT = (u16*)(ws + (48ull << 20));            // [48,52M)
  u16*   kwh  = (u16*)(ws + (52ull << 20));            // 512K
  u16*   vwT  = (u16*)(ws + (52ull << 20) + 524288);   // 512K
  char*  sm   = ws + (53ull << 20);                    // small region
  float* qs   = (float*)(sm);
  float* beta = (float*)(sm + 4096);                   // 16K
  float* Sp1  = (float*)(ws + (86ull << 20));          // [86,94M) split-K partial 1

  prep_all_kernel<<<dim3(2945), 256, 0, stream>>>(x, xh, pq, qh, qs, vw, vwT, kw, kwh, beta);
  sgemm_kernel<<<dim3(32, 4, 2), 256, 0, stream>>>(qh, xh, Sp0, Sp1);
  egemm_kernel<<<dim3(64, 8), 256, 0, stream>>>(kwh, Sp0, Sp1, E);
  softmax_kernel<<<dim3(32, 8), 256, 0, stream>>>(E, qs, kb, vb, attT, beta);
  wgemm_kernel<<<dim3(64, 8), 256, 0, stream>>>(attT, vwT, W);
  outgemm_kernel<<<dim3(32, 4, 8), 256, 0, stream>>>(W, xh, beta, gm, out);
}